// Round 2
// baseline (1056.042 us; speedup 1.0000x reference)
//
#include <hip/hip_runtime.h>
#include <hip/hip_fp16.h>
#include <cstdint>
#include <cstddef>

#define B_ROWS 16384
#define DX 128
#define DYDIM 128
#define HDIM 2048
#define NPARAM 49              // 3K+1
#define NCOL (DYDIM * NPARAM)  // 6272
#define CROWS 2048
#define NCHUNK (B_ROWS / CROWS)

typedef __attribute__((ext_vector_type(8))) _Float16 half8v;
typedef __attribute__((ext_vector_type(4))) float f32x4;

// ---------------- prep kernels ----------------
__global__ void k_f32_to_f16(const float* __restrict__ in, _Float16* __restrict__ out, int n) {
  int i = blockIdx.x * 256 + threadIdx.x;
  if (i < n) out[i] = (_Float16)in[i];
}

// out[c][r] = (f16) in[r][c];  in is [R][C], out is [C][R]. R,C multiples of 32.
__global__ void k_transpose_f16(const float* __restrict__ in, _Float16* __restrict__ out, int R, int C) {
  __shared__ float tile[32][33];
  int c0 = blockIdx.x * 32, r0 = blockIdx.y * 32;
  int tx = threadIdx.x;  // 0..31
  for (int i = threadIdx.y; i < 32; i += 8)
    tile[i][tx] = in[(size_t)(r0 + i) * C + c0 + tx];
  __syncthreads();
  for (int i = threadIdx.y; i < 32; i += 8)
    out[(size_t)(c0 + i) * R + r0 + tx] = (_Float16)tile[tx][i];
}

// ---------------- fp16 MFMA GEMM, B^T layout (m97 structure) ----------------
// A: [M][K] f16 row-major, Bt: [N][K] f16 row-major. C = A*B^T + bias.
// EPI==0: relu, store f16 to Ch. EPI==1: store f32 to Cf.
template <int EPI>
__global__ __launch_bounds__(256) void k_gemm_bt(
    const _Float16* __restrict__ A, const _Float16* __restrict__ Bt,
    const float* __restrict__ bias, _Float16* __restrict__ Ch,
    float* __restrict__ Cf, int M, int N, int K) {
  __shared__ _Float16 Abuf[128 * 32];
  __shared__ _Float16 Bbuf[128 * 32];
  const int t = threadIdx.x;
  const int l = t & 63;
  const int w = t >> 6;
  const int tileM = blockIdx.y * 128;
  const int tileN = blockIdx.x * 128;
  const int wm = w >> 1, wn = w & 1;

  // staging: thread t loads 16B; LDS tile layout [128 rows][32 k] f16 (64B/row)
  const int srow = w * 16 + (l >> 2);  // row within 64-row half
  const int skel = (l & 3) * 8;        // k element offset
  const char* Ag = (const char*)(A + (size_t)(tileM + srow) * K + skel);
  const char* Bg = (const char*)(Bt + (size_t)(tileN + srow) * K + skel);
  const size_t gRowStep = (size_t)64 * K * 2;  // +64 global rows

  auto ldsA = (__attribute__((address_space(3))) char*)Abuf;
  auto ldsB = (__attribute__((address_space(3))) char*)Bbuf;
  const int ldsBase = w * 1024;  // per-wave segment (64 lanes * 16B)

  f32x4 acc[4][4];
#pragma unroll
  for (int i = 0; i < 4; ++i)
#pragma unroll
    for (int j = 0; j < 4; ++j) acc[i][j] = (f32x4){0.f, 0.f, 0.f, 0.f};

  const int nk = K >> 5;

#define STAGE(kt)                                                                              \
  do {                                                                                         \
    size_t koff = (size_t)(kt) * 64;                                                           \
    __builtin_amdgcn_global_load_lds(                                                          \
        (const __attribute__((address_space(1))) uint32_t*)(Ag + koff),                        \
        (__attribute__((address_space(3))) uint32_t*)(ldsA + ldsBase), 16, 0, 0);              \
    __builtin_amdgcn_global_load_lds(                                                          \
        (const __attribute__((address_space(1))) uint32_t*)(Ag + koff + gRowStep),             \
        (__attribute__((address_space(3))) uint32_t*)(ldsA + 4096 + ldsBase), 16, 0, 0);       \
    __builtin_amdgcn_global_load_lds(                                                          \
        (const __attribute__((address_space(1))) uint32_t*)(Bg + koff),                        \
        (__attribute__((address_space(3))) uint32_t*)(ldsB + ldsBase), 16, 0, 0);              \
    __builtin_amdgcn_global_load_lds(                                                          \
        (const __attribute__((address_space(1))) uint32_t*)(Bg + koff + gRowStep),             \
        (__attribute__((address_space(3))) uint32_t*)(ldsB + 4096 + ldsBase), 16, 0, 0);       \
  } while (0)

  STAGE(0);
  const int abase = (wm * 64 + (l & 15)) * 32 + (l >> 4) * 8;
  const int bbase = (wn * 64 + (l & 15)) * 32 + (l >> 4) * 8;
  for (int kt = 0; kt < nk; ++kt) {
    __syncthreads();
    half8v av[4], bv[4];
#pragma unroll
    for (int mf = 0; mf < 4; ++mf)
      av[mf] = *(const half8v*)((const _Float16*)Abuf + abase + mf * 512);
#pragma unroll
    for (int nf = 0; nf < 4; ++nf)
      bv[nf] = *(const half8v*)((const _Float16*)Bbuf + bbase + nf * 512);
#pragma unroll
    for (int mf = 0; mf < 4; ++mf)
#pragma unroll
      for (int nf = 0; nf < 4; ++nf)
        acc[mf][nf] = __builtin_amdgcn_mfma_f32_16x16x32_f16(av[mf], bv[nf], acc[mf][nf], 0, 0, 0);
    __syncthreads();
    if (kt + 1 < nk) STAGE(kt + 1);
  }
#undef STAGE

  // epilogue: C/D layout col=lane&15, row=(lane>>4)*4+reg  [guide §3, m89-verified; dtype-independent]
  const int crow0 = tileM + wm * 64 + (l >> 4) * 4;
  const int ccol0 = tileN + wn * 64 + (l & 15);
#pragma unroll
  for (int nf = 0; nf < 4; ++nf) {
    const int col = ccol0 + nf * 16;
    const float bvv = bias[col];
#pragma unroll
    for (int mf = 0; mf < 4; ++mf) {
#pragma unroll
      for (int j = 0; j < 4; ++j) {
        const int row = crow0 + mf * 16 + j;
        float v = acc[mf][nf][j] + bvv;
        if (EPI == 0) {
          v = fmaxf(v, 0.f);
          Ch[(size_t)row * N + col] = (_Float16)v;
        } else {
          Cf[(size_t)row * N + col] = v;
        }
      }
    }
  }
}

// ---------------- spline epilogue ----------------
// one block (128 threads) per row b; thread d handles output dim d
__global__ __launch_bounds__(128) void k_spline(
    const float* __restrict__ pdf,  // [rows][NCOL]
    const float* __restrict__ y,    // [rows][DYDIM]
    float* __restrict__ out,        // [rows][DYDIM]
    float* __restrict__ dlogp) {    // [rows]
  __shared__ float row[NCOL];
  __shared__ float red[128];
  const int b = blockIdx.x;
  const int d = threadIdx.x;
  const float* p = pdf + (size_t)b * NCOL;
  for (int i = d; i < NCOL; i += 128) row[i] = p[i];
  __syncthreads();
  const float* q = &row[d * NPARAM];

  float mw = -1e30f, mh = -1e30f;
#pragma unroll
  for (int j = 0; j < 16; ++j) {
    mw = fmaxf(mw, q[j]);
    mh = fmaxf(mh, q[16 + j]);
  }
  float sw = 0.f, sh = 0.f;
#pragma unroll
  for (int j = 0; j < 16; ++j) {
    sw += __expf(q[j] - mw);
    sh += __expf(q[16 + j] - mh);
  }
  const float rw = 0.984f / sw, rh = 0.984f / sh;  // (1 - K*MIN_BIN) = 0.984
  const float yv = y[(size_t)b * DYDIM + d];

  // walk bins; capture the last bin whose left edge <= y (== reference idx)
  float cws = 0.f, chs = 0.f, xk = 0.f, yk = 0.f, wk = 1.f, hk = 1.f;
  int idx = 0;
#pragma unroll
  for (int j = 0; j < 16; ++j) {
    float wj = 0.001f + rw * __expf(q[j] - mw);
    float hj = 0.001f + rh * __expf(q[16 + j] - mh);
    if (yv >= cws) { idx = j; xk = cws; yk = chs; wk = wj; hk = hj; }
    cws += wj;
    chs += hj;
  }
  const float du0 = q[32 + idx], du1 = q[33 + idx];
  const float dk  = 0.001f + fmaxf(du0, 0.f) + log1pf(__expf(-fabsf(du0)));
  const float dk1 = 0.001f + fmaxf(du1, 0.f) + log1pf(__expf(-fabsf(du1)));

  const float s = hk / wk;
  const float tt = (yv - xk) / wk;
  const float omt = 1.f - tt;
  const float dnm = s + (dk1 + dk - 2.f * s) * tt * omt;
  const float o = yk + hk * (s * tt * tt + dk * tt * omt) / dnm;
  const float dr = s * s * (dk1 * tt * tt + 2.f * s * tt * omt + dk * omt * omt) / (dnm * dnm);

  out[(size_t)b * DYDIM + d] = o;
  red[d] = __logf(dr);
  __syncthreads();
#pragma unroll
  for (int s2 = 64; s2 > 0; s2 >>= 1) {
    if (d < s2) red[d] += red[d + s2];
    __syncthreads();
  }
  if (d == 0) dlogp[b] = red[0];
}

// ---------------- launch ----------------
extern "C" void kernel_launch(void* const* d_in, const int* in_sizes, int n_in,
                              void* d_out, int out_size, void* d_ws, size_t ws_size,
                              hipStream_t stream) {
  const float* x  = (const float*)d_in[0];
  const float* y  = (const float*)d_in[1];
  const float* W1 = (const float*)d_in[2];
  const float* b1 = (const float*)d_in[3];
  const float* W2 = (const float*)d_in[4];
  const float* b2 = (const float*)d_in[5];
  float* out = (float*)d_out;
  float* dlogp = out + (size_t)B_ROWS * DYDIM;

  char* ws = (char*)d_ws;
  _Float16* xb  = (_Float16*)ws;                       // B*DX f16
  _Float16* w1t = xb + (size_t)B_ROWS * DX;            // [HDIM][DX]
  _Float16* w2t = w1t + (size_t)HDIM * DX;             // [NCOL][HDIM]
  _Float16* h   = w2t + (size_t)NCOL * HDIM;           // [B][HDIM]
  float* pdfc = (float*)(h + (size_t)B_ROWS * HDIM);   // [CROWS][NCOL]

  k_f32_to_f16<<<(B_ROWS * DX + 255) / 256, 256, 0, stream>>>(x, xb, B_ROWS * DX);
  k_transpose_f16<<<dim3(HDIM / 32, DX / 32), dim3(32, 8), 0, stream>>>(W1, w1t, DX, HDIM);
  k_transpose_f16<<<dim3(NCOL / 32, HDIM / 32), dim3(32, 8), 0, stream>>>(W2, w2t, HDIM, NCOL);

  // h = relu(x @ W1 + b1), f16
  k_gemm_bt<0><<<dim3(HDIM / 128, B_ROWS / 128), 256, 0, stream>>>(
      xb, w1t, b1, h, nullptr, B_ROWS, HDIM, DX);

  for (int c = 0; c < NCHUNK; ++c) {
    const _Float16* hA = h + (size_t)c * CROWS * HDIM;
    k_gemm_bt<1><<<dim3(NCOL / 128, CROWS / 128), 256, 0, stream>>>(
        hA, w2t, b2, nullptr, pdfc, CROWS, NCOL, HDIM);
    k_spline<<<CROWS, 128, 0, stream>>>(pdfc, y + (size_t)c * CROWS * DYDIM,
                                        out + (size_t)c * CROWS * DYDIM,
                                        dlogp + (size_t)c * CROWS);
  }
}

// Round 3
// 754.459 us; speedup vs baseline: 1.3997x; 1.3997x over previous
//
#include <hip/hip_runtime.h>
#include <hip/hip_fp16.h>
#include <cstdint>
#include <cstddef>

#define B_ROWS 16384
#define DX 128
#define DYDIM 128
#define HDIM 2048
#define NPARAM 49              // 3K+1
#define NCOL (DYDIM * NPARAM)  // 6272
#define CROWS 8192
#define NCHUNK (B_ROWS / CROWS)

typedef __attribute__((ext_vector_type(8))) _Float16 half8v;
typedef __attribute__((ext_vector_type(4))) float f32x4;

// ---------------- prep kernels ----------------
__global__ void k_f32_to_f16(const float* __restrict__ in, _Float16* __restrict__ out, int n) {
  int i = blockIdx.x * 256 + threadIdx.x;
  if (i < n) out[i] = (_Float16)in[i];
}

// out[c][r] = (f16) in[r][c];  in is [R][C], out is [C][R]. R,C multiples of 32.
__global__ void k_transpose_f16(const float* __restrict__ in, _Float16* __restrict__ out, int R, int C) {
  __shared__ float tile[32][33];
  int c0 = blockIdx.x * 32, r0 = blockIdx.y * 32;
  int tx = threadIdx.x;  // 0..31
  for (int i = threadIdx.y; i < 32; i += 8)
    tile[i][tx] = in[(size_t)(r0 + i) * C + c0 + tx];
  __syncthreads();
  for (int i = threadIdx.y; i < 32; i += 8)
    out[(size_t)(c0 + i) * R + r0 + tx] = (_Float16)tile[tx][i];
}

// ---------------- fp16 MFMA GEMM, B^T layout (m97 structure + T1 swizzle) ----
// A: [M][K] f16 row-major, Bt: [N][K] f16 row-major. C = relu?(A*B^T + bias), f16.
template <bool RELU>
__global__ __launch_bounds__(256) void k_gemm_bt(
    const _Float16* __restrict__ A, const _Float16* __restrict__ Bt,
    const float* __restrict__ bias, _Float16* __restrict__ C,
    int M, int N, int K) {
  __shared__ _Float16 Abuf[128 * 32];
  __shared__ _Float16 Bbuf[128 * 32];
  const int t = threadIdx.x;
  const int l = t & 63;
  const int w = t >> 6;

  // XCD-aware bijective swizzle (T1): nwg % 8 == 0 for all our grids.
  int bx = blockIdx.x, by = blockIdx.y;
  {
    const int nx = gridDim.x;
    const int nwg = nx * gridDim.y;
    const int lin = by * nx + bx;
    const int cpx = nwg >> 3;
    const int sw = (lin & 7) * cpx + (lin >> 3);
    bx = sw % nx;
    by = sw / nx;
  }
  const int tileM = by * 128;
  const int tileN = bx * 128;
  const int wm = w >> 1, wn = w & 1;

  // staging: thread t loads 16B; LDS tile layout [128 rows][32 k] f16 (64B/row)
  const int srow = w * 16 + (l >> 2);  // row within 64-row half
  const int skel = (l & 3) * 8;        // k element offset
  const char* Ag = (const char*)(A + (size_t)(tileM + srow) * K + skel);
  const char* Bg = (const char*)(Bt + (size_t)(tileN + srow) * K + skel);
  const size_t gRowStep = (size_t)64 * K * 2;  // +64 global rows

  auto ldsA = (__attribute__((address_space(3))) char*)Abuf;
  auto ldsB = (__attribute__((address_space(3))) char*)Bbuf;
  const int ldsBase = w * 1024;  // per-wave segment (64 lanes * 16B)

  f32x4 acc[4][4];
#pragma unroll
  for (int i = 0; i < 4; ++i)
#pragma unroll
    for (int j = 0; j < 4; ++j) acc[i][j] = (f32x4){0.f, 0.f, 0.f, 0.f};

  const int nk = K >> 5;

#define STAGE(kt)                                                                              \
  do {                                                                                         \
    size_t koff = (size_t)(kt) * 64;                                                           \
    __builtin_amdgcn_global_load_lds(                                                          \
        (const __attribute__((address_space(1))) uint32_t*)(Ag + koff),                        \
        (__attribute__((address_space(3))) uint32_t*)(ldsA + ldsBase), 16, 0, 0);              \
    __builtin_amdgcn_global_load_lds(                                                          \
        (const __attribute__((address_space(1))) uint32_t*)(Ag + koff + gRowStep),             \
        (__attribute__((address_space(3))) uint32_t*)(ldsA + 4096 + ldsBase), 16, 0, 0);       \
    __builtin_amdgcn_global_load_lds(                                                          \
        (const __attribute__((address_space(1))) uint32_t*)(Bg + koff),                        \
        (__attribute__((address_space(3))) uint32_t*)(ldsB + ldsBase), 16, 0, 0);              \
    __builtin_amdgcn_global_load_lds(                                                          \
        (const __attribute__((address_space(1))) uint32_t*)(Bg + koff + gRowStep),             \
        (__attribute__((address_space(3))) uint32_t*)(ldsB + 4096 + ldsBase), 16, 0, 0);       \
  } while (0)

  STAGE(0);
  const int abase = (wm * 64 + (l & 15)) * 32 + (l >> 4) * 8;
  const int bbase = (wn * 64 + (l & 15)) * 32 + (l >> 4) * 8;
  for (int kt = 0; kt < nk; ++kt) {
    __syncthreads();
    half8v av[4], bv[4];
#pragma unroll
    for (int mf = 0; mf < 4; ++mf)
      av[mf] = *(const half8v*)((const _Float16*)Abuf + abase + mf * 512);
#pragma unroll
    for (int nf = 0; nf < 4; ++nf)
      bv[nf] = *(const half8v*)((const _Float16*)Bbuf + bbase + nf * 512);
#pragma unroll
    for (int mf = 0; mf < 4; ++mf)
#pragma unroll
      for (int nf = 0; nf < 4; ++nf)
        acc[mf][nf] = __builtin_amdgcn_mfma_f32_16x16x32_f16(av[mf], bv[nf], acc[mf][nf], 0, 0, 0);
    __syncthreads();
    if (kt + 1 < nk) STAGE(kt + 1);
  }
#undef STAGE

  // epilogue: C/D layout col=lane&15, row=(lane>>4)*4+reg  [guide §3, m89-verified]
  const int crow0 = tileM + wm * 64 + (l >> 4) * 4;
  const int ccol0 = tileN + wn * 64 + (l & 15);
#pragma unroll
  for (int nf = 0; nf < 4; ++nf) {
    const int col = ccol0 + nf * 16;
    const float bvv = bias[col];
#pragma unroll
    for (int mf = 0; mf < 4; ++mf) {
#pragma unroll
      for (int j = 0; j < 4; ++j) {
        const int row = crow0 + mf * 16 + j;
        float v = acc[mf][nf][j] + bvv;
        if (RELU) v = fmaxf(v, 0.f);
        C[(size_t)row * N + col] = (_Float16)v;
      }
    }
  }
}

// ---------------- spline epilogue ----------------
// one block (128 threads) per row b; thread d handles output dim d
__global__ __launch_bounds__(128) void k_spline(
    const _Float16* __restrict__ pdf,  // [rows][NCOL] f16
    const float* __restrict__ y,       // [rows][DYDIM]
    float* __restrict__ out,           // [rows][DYDIM]
    float* __restrict__ dlogp) {       // [rows]
  alignas(16) __shared__ _Float16 row16[NCOL];
  __shared__ float red[128];
  const int b = blockIdx.x;
  const int d = threadIdx.x;
  const _Float16* p = pdf + (size_t)b * NCOL;
  for (int i = d; i < NCOL / 8; i += 128)
    ((half8v*)row16)[i] = ((const half8v*)p)[i];
  __syncthreads();
  const _Float16* q = &row16[d * NPARAM];

  float mw = -1e30f, mh = -1e30f;
#pragma unroll
  for (int j = 0; j < 16; ++j) {
    mw = fmaxf(mw, (float)q[j]);
    mh = fmaxf(mh, (float)q[16 + j]);
  }
  float sw = 0.f, sh = 0.f;
#pragma unroll
  for (int j = 0; j < 16; ++j) {
    sw += __expf((float)q[j] - mw);
    sh += __expf((float)q[16 + j] - mh);
  }
  const float rw = 0.984f / sw, rh = 0.984f / sh;  // (1 - K*MIN_BIN) = 0.984
  const float yv = y[(size_t)b * DYDIM + d];

  // walk bins; capture the last bin whose left edge <= y (== reference idx)
  float cws = 0.f, chs = 0.f, xk = 0.f, yk = 0.f, wk = 1.f, hk = 1.f;
  int idx = 0;
#pragma unroll
  for (int j = 0; j < 16; ++j) {
    float wj = 0.001f + rw * __expf((float)q[j] - mw);
    float hj = 0.001f + rh * __expf((float)q[16 + j] - mh);
    if (yv >= cws) { idx = j; xk = cws; yk = chs; wk = wj; hk = hj; }
    cws += wj;
    chs += hj;
  }
  const float du0 = (float)q[32 + idx], du1 = (float)q[33 + idx];
  const float dk  = 0.001f + fmaxf(du0, 0.f) + log1pf(__expf(-fabsf(du0)));
  const float dk1 = 0.001f + fmaxf(du1, 0.f) + log1pf(__expf(-fabsf(du1)));

  const float s = hk / wk;
  const float tt = (yv - xk) / wk;
  const float omt = 1.f - tt;
  const float dnm = s + (dk1 + dk - 2.f * s) * tt * omt;
  const float o = yk + hk * (s * tt * tt + dk * tt * omt) / dnm;
  const float dr = s * s * (dk1 * tt * tt + 2.f * s * tt * omt + dk * omt * omt) / (dnm * dnm);

  out[(size_t)b * DYDIM + d] = o;
  red[d] = __logf(dr);
  __syncthreads();
#pragma unroll
  for (int s2 = 64; s2 > 0; s2 >>= 1) {
    if (d < s2) red[d] += red[d + s2];
    __syncthreads();
  }
  if (d == 0) dlogp[b] = red[0];
}

// ---------------- launch ----------------
extern "C" void kernel_launch(void* const* d_in, const int* in_sizes, int n_in,
                              void* d_out, int out_size, void* d_ws, size_t ws_size,
                              hipStream_t stream) {
  const float* x  = (const float*)d_in[0];
  const float* y  = (const float*)d_in[1];
  const float* W1 = (const float*)d_in[2];
  const float* b1 = (const float*)d_in[3];
  const float* W2 = (const float*)d_in[4];
  const float* b2 = (const float*)d_in[5];
  float* out = (float*)d_out;
  float* dlogp = out + (size_t)B_ROWS * DYDIM;

  char* ws = (char*)d_ws;
  _Float16* xb  = (_Float16*)ws;                       // [B][DX]
  _Float16* w1t = xb + (size_t)B_ROWS * DX;            // [HDIM][DX]
  _Float16* w2t = w1t + (size_t)HDIM * DX;             // [NCOL][HDIM]
  _Float16* h   = w2t + (size_t)NCOL * HDIM;           // [B][HDIM]
  _Float16* pdfc = h + (size_t)B_ROWS * HDIM;          // [CROWS][NCOL] f16

  k_f32_to_f16<<<(B_ROWS * DX + 255) / 256, 256, 0, stream>>>(x, xb, B_ROWS * DX);
  k_transpose_f16<<<dim3(HDIM / 32, DX / 32), dim3(32, 8), 0, stream>>>(W1, w1t, DX, HDIM);
  k_transpose_f16<<<dim3(NCOL / 32, HDIM / 32), dim3(32, 8), 0, stream>>>(W2, w2t, HDIM, NCOL);

  // h = relu(x @ W1 + b1), f16.  grid 16*128=2048 blocks (%8==0)
  k_gemm_bt<true><<<dim3(HDIM / 128, B_ROWS / 128), 256, 0, stream>>>(
      xb, w1t, b1, h, B_ROWS, HDIM, DX);

  for (int c = 0; c < NCHUNK; ++c) {
    const _Float16* hA = h + (size_t)c * CROWS * HDIM;
    // grid 49*64=3136 blocks (%8==0)
    k_gemm_bt<false><<<dim3(NCOL / 128, CROWS / 128), 256, 0, stream>>>(
        hA, w2t, b2, pdfc, CROWS, NCOL, HDIM);
    k_spline<<<CROWS, 128, 0, stream>>>(pdfc, y + (size_t)c * CROWS * DYDIM,
                                        out + (size_t)c * CROWS * DYDIM,
                                        dlogp + (size_t)c * CROWS);
  }
}

// Round 4
// 642.817 us; speedup vs baseline: 1.6428x; 1.1737x over previous
//
#include <hip/hip_runtime.h>
#include <hip/hip_fp16.h>
#include <cstdint>
#include <cstddef>

#define B_ROWS 16384
#define DX 128
#define DYDIM 128
#define HDIM 2048
#define NPARAM 49              // 3K+1
#define NCOL 6272              // DYDIM*NPARAM
#define NPAD 6400              // 25*256 padded N for 256-tile GEMM2
#define CROWS 8192
#define NCHUNK (B_ROWS / CROWS)

typedef __attribute__((ext_vector_type(8))) _Float16 half8v;
typedef __attribute__((ext_vector_type(4))) float f32x4;

// ---------------- prep kernels ----------------
__global__ void k_f32_to_f16(const float* __restrict__ in, _Float16* __restrict__ out, int n) {
  int i = blockIdx.x * 256 + threadIdx.x;
  if (i < n) out[i] = (_Float16)in[i];
}

__global__ void k_transpose_f16(const float* __restrict__ in, _Float16* __restrict__ out, int R, int C) {
  __shared__ float tile[32][33];
  int c0 = blockIdx.x * 32, r0 = blockIdx.y * 32;
  int tx = threadIdx.x;
  for (int i = threadIdx.y; i < 32; i += 8)
    tile[i][tx] = in[(size_t)(r0 + i) * C + c0 + tx];
  __syncthreads();
  for (int i = threadIdx.y; i < 32; i += 8)
    out[(size_t)(c0 + i) * R + r0 + tx] = (_Float16)tile[tx][i];
}

// ---------------- GEMM1: m97 128^2 structure (relu, f16 out) ----------------
__global__ __launch_bounds__(256) void k_gemm1(
    const _Float16* __restrict__ A, const _Float16* __restrict__ Bt,
    const float* __restrict__ bias, _Float16* __restrict__ C,
    int M, int N, int K) {
  __shared__ _Float16 Abuf[128 * 32];
  __shared__ _Float16 Bbuf[128 * 32];
  const int t = threadIdx.x;
  const int l = t & 63;
  const int w = t >> 6;
  int bx = blockIdx.x, by = blockIdx.y;
  {
    const int nx = gridDim.x;
    const int nwg = nx * gridDim.y;
    const int lin = by * nx + bx;
    const int cpx = nwg >> 3;
    const int sw = (lin & 7) * cpx + (lin >> 3);
    bx = sw % nx;
    by = sw / nx;
  }
  const int tileM = by * 128;
  const int tileN = bx * 128;
  const int wm = w >> 1, wn = w & 1;
  const int srow = w * 16 + (l >> 2);
  const int skel = (l & 3) * 8;
  const char* Ag = (const char*)(A + (size_t)(tileM + srow) * K + skel);
  const char* Bg = (const char*)(Bt + (size_t)(tileN + srow) * K + skel);
  const size_t gRowStep = (size_t)64 * K * 2;
  auto ldsA = (__attribute__((address_space(3))) char*)Abuf;
  auto ldsB = (__attribute__((address_space(3))) char*)Bbuf;
  const int ldsBase = w * 1024;
  f32x4 acc[4][4];
#pragma unroll
  for (int i = 0; i < 4; ++i)
#pragma unroll
    for (int j = 0; j < 4; ++j) acc[i][j] = (f32x4){0.f, 0.f, 0.f, 0.f};
  const int nk = K >> 5;
#define STAGE1(kt)                                                                             \
  do {                                                                                         \
    size_t koff = (size_t)(kt) * 64;                                                           \
    __builtin_amdgcn_global_load_lds(                                                          \
        (const __attribute__((address_space(1))) uint32_t*)(Ag + koff),                        \
        (__attribute__((address_space(3))) uint32_t*)(ldsA + ldsBase), 16, 0, 0);              \
    __builtin_amdgcn_global_load_lds(                                                          \
        (const __attribute__((address_space(1))) uint32_t*)(Ag + koff + gRowStep),             \
        (__attribute__((address_space(3))) uint32_t*)(ldsA + 4096 + ldsBase), 16, 0, 0);       \
    __builtin_amdgcn_global_load_lds(                                                          \
        (const __attribute__((address_space(1))) uint32_t*)(Bg + koff),                        \
        (__attribute__((address_space(3))) uint32_t*)(ldsB + ldsBase), 16, 0, 0);              \
    __builtin_amdgcn_global_load_lds(                                                          \
        (const __attribute__((address_space(1))) uint32_t*)(Bg + koff + gRowStep),             \
        (__attribute__((address_space(3))) uint32_t*)(ldsB + 4096 + ldsBase), 16, 0, 0);       \
  } while (0)
  STAGE1(0);
  const int abase = (wm * 64 + (l & 15)) * 32 + (l >> 4) * 8;
  const int bbase = (wn * 64 + (l & 15)) * 32 + (l >> 4) * 8;
  for (int kt = 0; kt < nk; ++kt) {
    __syncthreads();
    half8v av[4], bv[4];
#pragma unroll
    for (int mf = 0; mf < 4; ++mf)
      av[mf] = *(const half8v*)((const _Float16*)Abuf + abase + mf * 512);
#pragma unroll
    for (int nf = 0; nf < 4; ++nf)
      bv[nf] = *(const half8v*)((const _Float16*)Bbuf + bbase + nf * 512);
#pragma unroll
    for (int mf = 0; mf < 4; ++mf)
#pragma unroll
      for (int nf = 0; nf < 4; ++nf)
        acc[mf][nf] = __builtin_amdgcn_mfma_f32_16x16x32_f16(av[mf], bv[nf], acc[mf][nf], 0, 0, 0);
    __syncthreads();
    if (kt + 1 < nk) STAGE1(kt + 1);
  }
#undef STAGE1
  const int crow0 = tileM + wm * 64 + (l >> 4) * 4;
  const int ccol0 = tileN + wn * 64 + (l & 15);
#pragma unroll
  for (int nf = 0; nf < 4; ++nf) {
    const int col = ccol0 + nf * 16;
    const float bvv = bias[col];
#pragma unroll
    for (int mf = 0; mf < 4; ++mf) {
#pragma unroll
      for (int j = 0; j < 4; ++j) {
        const int row = crow0 + mf * 16 + j;
        float v = fmaxf(acc[mf][nf][j] + bvv, 0.f);
        C[(size_t)row * N + col] = (_Float16)v;
      }
    }
  }
}

// ---------------- GEMM2: 256^2 8-phase template (T2+T3+T4+T5, plain HIP) ----
// A: [M][2048] f16, Bt: [6272+pad][2048] f16, C: [M][6400] f16 = A*Bt^T + bias
__global__ __launch_bounds__(512, 2) void k_gemm2(
    const _Float16* __restrict__ A, const _Float16* __restrict__ Bt,
    const float* __restrict__ bias, _Float16* __restrict__ C, int M) {
  constexpr int K = HDIM;       // 2048
  constexpr int K2 = K * 2;     // row bytes
  constexpr int NT = K / 64;    // 32 K-tiles
  constexpr int ITERS = NT / 2; // 16

  __shared__ char smem[131072];  // A: [2 dbuf][2 half][16KB] @0; B same @65536

  const int t = threadIdx.x;
  const int l = t & 63;
  const int w = t >> 6;    // 0..7
  const int wm = w >> 2;   // 0..1
  const int wn = w & 3;    // 0..3
  const int rlo = l & 15;
  const int khi = l >> 4;
  const int wOff = w * 1024;

  int bx = blockIdx.x, by = blockIdx.y;
  {
    const int nx = gridDim.x;
    const int nwg = nx * gridDim.y;
    const int lin = by * nx + bx;
    const int cpx = nwg >> 3;
    const int sw = (lin & 7) * cpx + (lin >> 3);
    bx = sw % nx;
    by = sw / nx;
  }
  const int tileM = by * 256;
  const int tileN = bx * 256;

  // staging source decode: LDS phys -> logical (involution: bit9 -> bit5)
  int rowj[2], kbj[2];
#pragma unroll
  for (int j = 0; j < 2; ++j) {
    const int phys = j * 8192 + t * 16;
    const int b = phys ^ (((phys >> 9) & 1) << 5);
    rowj[j] = ((b >> 11) << 4) + ((b >> 6) & 15);
    kbj[j] = (((b >> 10) & 1) << 6) + (b & 63);
  }
  const char* pA[2][2];
  const char* pB[2][2];
#pragma unroll
  for (int half = 0; half < 2; ++half)
#pragma unroll
    for (int j = 0; j < 2; ++j) {
      pA[half][j] = (const char*)A + (size_t)(tileM + half * 128 + rowj[j]) * K2 + kbj[j];
      pB[half][j] = (const char*)Bt + (size_t)(tileN + half * 128 + rowj[j]) * K2 + kbj[j];
    }

  auto lds3 = (__attribute__((address_space(3))) char*)smem;

#define LDSA(d, half) ((d) * 32768 + (half) * 16384)
#define LDSB(d, half) (65536 + (d) * 32768 + (half) * 16384)
#define GLDS(srcp, ldsoff)                                                                   \
  __builtin_amdgcn_global_load_lds(                                                           \
      (const __attribute__((address_space(1))) uint32_t*)(srcp),                              \
      (__attribute__((address_space(3))) uint32_t*)(lds3 + (ldsoff) + wOff), 16, 0, 0)
#define STG(op, d, half, kt)                                                                  \
  do {                                                                                        \
    GLDS(p##op[half][0] + (size_t)(kt) * 128, LDS##op(d, half));                              \
    GLDS(p##op[half][1] + (size_t)(kt) * 128, LDS##op(d, half) + 8192);                       \
  } while (0)
#define STG2(kt)                                                                              \
  do { STG(A, 0, 1, kt); STG(B, 0, 0, kt); } while (0)
#define VMCNT4 asm volatile("s_waitcnt vmcnt(4)" ::: "memory")
#define VMCNT0 asm volatile("s_waitcnt vmcnt(0)" ::: "memory")
#define NOSTG ((void)0)
#define CFENCE asm volatile("" ::: "memory")

  // read-address bases (swizzled): aoff(f,ks) = aBase + f*2048 + ks*1024
  const int swz = (rlo & 8) ? 32 : 0;
  const int aBase = wm * 8192 + rlo * 64 + ((khi * 16) ^ swz);
  const int bBase = wn * 4096 + rlo * 64 + ((khi * 16) ^ swz);

  f32x4 acc[8][4];
#pragma unroll
  for (int i = 0; i < 8; ++i)
#pragma unroll
    for (int j = 0; j < 4; ++j) acc[i][j] = (f32x4){0.f, 0.f, 0.f, 0.f};

#define MF(fi, gj, av, bv) \
  acc[fi][gj] = __builtin_amdgcn_mfma_f32_16x16x32_f16(av, bv, acc[fi][gj], 0, 0, 0)

#define PH(d, mq, nq, STAGES, WAITS)                                                          \
  do {                                                                                        \
    const int aB = (d) * 32768 + (mq) * 16384 + aBase;                                        \
    const int bB = 65536 + (d) * 32768 + (nq) * 16384 + bBase;                                \
    half8v a00 = *(const half8v*)(smem + aB);                                                 \
    half8v a01 = *(const half8v*)(smem + aB + 1024);                                          \
    half8v a10 = *(const half8v*)(smem + aB + 2048);                                          \
    half8v a11 = *(const half8v*)(smem + aB + 3072);                                          \
    half8v a20 = *(const half8v*)(smem + aB + 4096);                                          \
    half8v a21 = *(const half8v*)(smem + aB + 5120);                                          \
    half8v a30 = *(const half8v*)(smem + aB + 6144);                                          \
    half8v a31 = *(const half8v*)(smem + aB + 7168);                                          \
    half8v b00 = *(const half8v*)(smem + bB);                                                 \
    half8v b01 = *(const half8v*)(smem + bB + 1024);                                          \
    half8v b10 = *(const half8v*)(smem + bB + 2048);                                          \
    half8v b11 = *(const half8v*)(smem + bB + 3072);                                          \
    STAGES;                                                                                   \
    WAITS;                                                                                    \
    CFENCE;                                                                                   \
    __builtin_amdgcn_s_barrier();                                                             \
    asm volatile("s_waitcnt lgkmcnt(0)" ::: "memory");                                        \
    __builtin_amdgcn_s_setprio(1);                                                            \
    MF((mq)*4 + 0, (nq)*2 + 0, a00, b00); MF((mq)*4 + 0, (nq)*2 + 0, a01, b01);               \
    MF((mq)*4 + 0, (nq)*2 + 1, a00, b10); MF((mq)*4 + 0, (nq)*2 + 1, a01, b11);               \
    MF((mq)*4 + 1, (nq)*2 + 0, a10, b00); MF((mq)*4 + 1, (nq)*2 + 0, a11, b01);               \
    MF((mq)*4 + 1, (nq)*2 + 1, a10, b10); MF((mq)*4 + 1, (nq)*2 + 1, a11, b11);               \
    MF((mq)*4 + 2, (nq)*2 + 0, a20, b00); MF((mq)*4 + 2, (nq)*2 + 0, a21, b01);               \
    MF((mq)*4 + 2, (nq)*2 + 1, a20, b10); MF((mq)*4 + 2, (nq)*2 + 1, a21, b11);               \
    MF((mq)*4 + 3, (nq)*2 + 0, a30, b00); MF((mq)*4 + 3, (nq)*2 + 0, a31, b01);               \
    MF((mq)*4 + 3, (nq)*2 + 1, a30, b10); MF((mq)*4 + 3, (nq)*2 + 1, a31, b11);               \
    __builtin_amdgcn_s_setprio(0);                                                            \
    CFENCE;                                                                                   \
    __builtin_amdgcn_s_barrier();                                                             \
  } while (0)

  // prologue: tile0 full -> buf0; tile1 A0,B1 -> buf1; wait tile0 landed
  STG(A, 0, 0, 0);
  STG(B, 0, 1, 0);
  STG(A, 0, 1, 0);
  STG(B, 0, 0, 0);
  STG(A, 1, 0, 1);
  STG(B, 1, 1, 1);
  VMCNT4;
  CFENCE;
  __builtin_amdgcn_s_barrier();

  for (int it = 0; it < ITERS - 1; ++it) {
    const int kt = 2 * it;
    PH(0, 0, 0, STG(A, 1, 1, kt + 1), NOSTG);  // ph1: read A0,B0(buf0); stage A1(t+1)
    PH(0, 0, 1, STG(B, 1, 0, kt + 1), NOSTG);  // ph2: stage B0(t+1)
    PH(0, 1, 1, STG(A, 0, 0, kt + 2), NOSTG);  // ph3: stage A0(t+2)
    PH(0, 1, 0, STG(B, 0, 1, kt + 2), VMCNT4); // ph4: stage B1(t+2); vmcnt(4)
    PH(1, 0, 0, STG2(kt + 2), NOSTG);          // ph5: stage A1,B0(t+2)
    PH(1, 0, 1, NOSTG, NOSTG);                 // ph6
    PH(1, 1, 1, STG(A, 1, 0, kt + 3), NOSTG);  // ph7: stage A0(t+3)
    PH(1, 1, 0, STG(B, 1, 1, kt + 3), VMCNT4); // ph8: stage B1(t+3); vmcnt(4)
  }
  // tail iteration: tiles NT-2 (buf0), NT-1 (buf1)
  PH(0, 0, 0, STG(A, 1, 1, NT - 1), NOSTG);
  PH(0, 0, 1, STG(B, 1, 0, NT - 1), NOSTG);
  PH(0, 1, 1, NOSTG, NOSTG);
  PH(0, 1, 0, NOSTG, VMCNT0);
  PH(1, 0, 0, NOSTG, NOSTG);
  PH(1, 0, 1, NOSTG, NOSTG);
  PH(1, 1, 1, NOSTG, NOSTG);
  PH(1, 1, 0, NOSTG, NOSTG);

#undef PH
#undef MF
#undef STG
#undef STG2
#undef GLDS
#undef LDSA
#undef LDSB

  // epilogue: C/D layout col=lane&15, row=(lane>>4)*4+j (m89-verified)
#pragma unroll
  for (int fi = 0; fi < 8; ++fi) {
    const int r0 = tileM + (((fi >> 2) * 2 + wm) << 6) + ((fi & 3) << 4) + khi * 4;
#pragma unroll
    for (int gj = 0; gj < 4; ++gj) {
      const int c = tileN + (((gj >> 1) * 4 + wn) << 5) + ((gj & 1) << 4) + rlo;
      const float bvv = (c < NCOL) ? bias[c] : 0.f;
#pragma unroll
      for (int j = 0; j < 4; ++j)
        C[(size_t)(r0 + j) * NPAD + c] = (_Float16)(acc[fi][gj][j] + bvv);
    }
  }
}

// ---------------- spline epilogue ----------------
__global__ __launch_bounds__(128) void k_spline(
    const _Float16* __restrict__ pdf,  // [rows][NPAD] f16
    const float* __restrict__ y,       // [rows][DYDIM]
    float* __restrict__ out,           // [rows][DYDIM]
    float* __restrict__ dlogp) {       // [rows]
  alignas(16) __shared__ _Float16 row16[NCOL];
  __shared__ float red[128];
  const int b = blockIdx.x;
  const int d = threadIdx.x;
  const _Float16* p = pdf + (size_t)b * NPAD;
  for (int i = d; i < NCOL / 8; i += 128)
    ((half8v*)row16)[i] = ((const half8v*)p)[i];
  __syncthreads();
  const _Float16* q = &row16[d * NPARAM];

  float mw = -1e30f, mh = -1e30f;
#pragma unroll
  for (int j = 0; j < 16; ++j) {
    mw = fmaxf(mw, (float)q[j]);
    mh = fmaxf(mh, (float)q[16 + j]);
  }
  float sw = 0.f, sh = 0.f;
#pragma unroll
  for (int j = 0; j < 16; ++j) {
    sw += __expf((float)q[j] - mw);
    sh += __expf((float)q[16 + j] - mh);
  }
  const float rw = 0.984f / sw, rh = 0.984f / sh;
  const float yv = y[(size_t)b * DYDIM + d];

  float cws = 0.f, chs = 0.f, xk = 0.f, yk = 0.f, wk = 1.f, hk = 1.f;
  int idx = 0;
#pragma unroll
  for (int j = 0; j < 16; ++j) {
    float wj = 0.001f + rw * __expf((float)q[j] - mw);
    float hj = 0.001f + rh * __expf((float)q[16 + j] - mh);
    if (yv >= cws) { idx = j; xk = cws; yk = chs; wk = wj; hk = hj; }
    cws += wj;
    chs += hj;
  }
  const float du0 = (float)q[32 + idx], du1 = (float)q[33 + idx];
  const float dk  = 0.001f + fmaxf(du0, 0.f) + log1pf(__expf(-fabsf(du0)));
  const float dk1 = 0.001f + fmaxf(du1, 0.f) + log1pf(__expf(-fabsf(du1)));

  const float s = hk / wk;
  const float tt = (yv - xk) / wk;
  const float omt = 1.f - tt;
  const float dnm = s + (dk1 + dk - 2.f * s) * tt * omt;
  const float o = yk + hk * (s * tt * tt + dk * tt * omt) / dnm;
  const float dr = s * s * (dk1 * tt * tt + 2.f * s * tt * omt + dk * omt * omt) / (dnm * dnm);

  out[(size_t)b * DYDIM + d] = o;
  red[d] = __logf(dr);
  __syncthreads();
#pragma unroll
  for (int s2 = 64; s2 > 0; s2 >>= 1) {
    if (d < s2) red[d] += red[d + s2];
    __syncthreads();
  }
  if (d == 0) dlogp[b] = red[0];
}

// ---------------- launch ----------------
extern "C" void kernel_launch(void* const* d_in, const int* in_sizes, int n_in,
                              void* d_out, int out_size, void* d_ws, size_t ws_size,
                              hipStream_t stream) {
  const float* x  = (const float*)d_in[0];
  const float* y  = (const float*)d_in[1];
  const float* W1 = (const float*)d_in[2];
  const float* b1 = (const float*)d_in[3];
  const float* W2 = (const float*)d_in[4];
  const float* b2 = (const float*)d_in[5];
  float* out = (float*)d_out;
  float* dlogp = out + (size_t)B_ROWS * DYDIM;

  char* ws = (char*)d_ws;
  _Float16* xb  = (_Float16*)ws;                       // [B][DX]
  _Float16* w1t = xb + (size_t)B_ROWS * DX;            // [HDIM][DX]
  _Float16* w2t = w1t + (size_t)HDIM * DX;             // [NCOL][HDIM]
  _Float16* h   = w2t + (size_t)NCOL * HDIM;           // [B][HDIM]
  _Float16* pdfc = h + (size_t)B_ROWS * HDIM;          // [CROWS][NPAD] f16

  k_f32_to_f16<<<(B_ROWS * DX + 255) / 256, 256, 0, stream>>>(x, xb, B_ROWS * DX);
  k_transpose_f16<<<dim3(HDIM / 32, DX / 32), dim3(32, 8), 0, stream>>>(W1, w1t, DX, HDIM);
  k_transpose_f16<<<dim3(NCOL / 32, HDIM / 32), dim3(32, 8), 0, stream>>>(W2, w2t, HDIM, NCOL);

  // h = relu(x @ W1 + b1), f16.  grid 16*128=2048 blocks
  k_gemm1<<<dim3(HDIM / 128, B_ROWS / 128), 256, 0, stream>>>(
      xb, w1t, b1, h, B_ROWS, HDIM, DX);

  for (int c = 0; c < NCHUNK; ++c) {
    const _Float16* hA = h + (size_t)c * CROWS * HDIM;
    // grid 25*32 = 800 blocks (%8==0)
    k_gemm2<<<dim3(NPAD / 256, CROWS / 256), 512, 0, stream>>>(hA, w2t, b2, pdfc, CROWS);
    k_spline<<<CROWS, 128, 0, stream>>>(pdfc, y + (size_t)c * CROWS * DYDIM,
                                        out + (size_t)c * CROWS * DYDIM,
                                        dlogp + (size_t)c * CROWS);
  }
}

// Round 5
// 601.039 us; speedup vs baseline: 1.7570x; 1.0695x over previous
//
#include <hip/hip_runtime.h>
#include <hip/hip_fp16.h>
#include <cstdint>
#include <cstddef>

#define B_ROWS 16384
#define DX 128
#define DYDIM 128
#define HDIM 2048
#define NPARAM 49              // 3K+1
#define NCOL 6272              // DYDIM*NPARAM
#define NPAD 6400              // 25*256 padded N for 256-tile GEMM2

typedef __attribute__((ext_vector_type(8))) _Float16 half8v;
typedef __attribute__((ext_vector_type(4))) float f32x4;

// ---------------- prep kernels ----------------
__global__ void k_f32_to_f16(const float* __restrict__ in, _Float16* __restrict__ out, int n) {
  int i = blockIdx.x * 256 + threadIdx.x;
  if (i < n) out[i] = (_Float16)in[i];
}

__global__ void k_transpose_f16(const float* __restrict__ in, _Float16* __restrict__ out, int R, int C) {
  __shared__ float tile[32][33];
  int c0 = blockIdx.x * 32, r0 = blockIdx.y * 32;
  int tx = threadIdx.x;
  for (int i = threadIdx.y; i < 32; i += 8)
    tile[i][tx] = in[(size_t)(r0 + i) * C + c0 + tx];
  __syncthreads();
  for (int i = threadIdx.y; i < 32; i += 8)
    out[(size_t)(c0 + i) * R + r0 + tx] = (_Float16)tile[tx][i];
}

// ---------------- GEMM1: m97 128^2 structure (relu, f16 out) ----------------
__global__ __launch_bounds__(256) void k_gemm1(
    const _Float16* __restrict__ A, const _Float16* __restrict__ Bt,
    const float* __restrict__ bias, _Float16* __restrict__ C,
    int M, int N, int K) {
  __shared__ _Float16 Abuf[128 * 32];
  __shared__ _Float16 Bbuf[128 * 32];
  const int t = threadIdx.x;
  const int l = t & 63;
  const int w = t >> 6;
  int bx = blockIdx.x, by = blockIdx.y;
  {
    const int nx = gridDim.x;
    const int nwg = nx * gridDim.y;
    const int lin = by * nx + bx;
    const int cpx = nwg >> 3;
    const int sw = (lin & 7) * cpx + (lin >> 3);
    bx = sw % nx;
    by = sw / nx;
  }
  const int tileM = by * 128;
  const int tileN = bx * 128;
  const int wm = w >> 1, wn = w & 1;
  const int srow = w * 16 + (l >> 2);
  const int skel = (l & 3) * 8;
  const char* Ag = (const char*)(A + (size_t)(tileM + srow) * K + skel);
  const char* Bg = (const char*)(Bt + (size_t)(tileN + srow) * K + skel);
  const size_t gRowStep = (size_t)64 * K * 2;
  auto ldsA = (__attribute__((address_space(3))) char*)Abuf;
  auto ldsB = (__attribute__((address_space(3))) char*)Bbuf;
  const int ldsBase = w * 1024;
  f32x4 acc[4][4];
#pragma unroll
  for (int i = 0; i < 4; ++i)
#pragma unroll
    for (int j = 0; j < 4; ++j) acc[i][j] = (f32x4){0.f, 0.f, 0.f, 0.f};
  const int nk = K >> 5;
#define STAGE1(kt)                                                                             \
  do {                                                                                         \
    size_t koff = (size_t)(kt) * 64;                                                           \
    __builtin_amdgcn_global_load_lds(                                                          \
        (const __attribute__((address_space(1))) uint32_t*)(Ag + koff),                        \
        (__attribute__((address_space(3))) uint32_t*)(ldsA + ldsBase), 16, 0, 0);              \
    __builtin_amdgcn_global_load_lds(                                                          \
        (const __attribute__((address_space(1))) uint32_t*)(Ag + koff + gRowStep),             \
        (__attribute__((address_space(3))) uint32_t*)(ldsA + 4096 + ldsBase), 16, 0, 0);       \
    __builtin_amdgcn_global_load_lds(                                                          \
        (const __attribute__((address_space(1))) uint32_t*)(Bg + koff),                        \
        (__attribute__((address_space(3))) uint32_t*)(ldsB + ldsBase), 16, 0, 0);              \
    __builtin_amdgcn_global_load_lds(                                                          \
        (const __attribute__((address_space(1))) uint32_t*)(Bg + koff + gRowStep),             \
        (__attribute__((address_space(3))) uint32_t*)(ldsB + 4096 + ldsBase), 16, 0, 0);       \
  } while (0)
  STAGE1(0);
  const int abase = (wm * 64 + (l & 15)) * 32 + (l >> 4) * 8;
  const int bbase = (wn * 64 + (l & 15)) * 32 + (l >> 4) * 8;
  for (int kt = 0; kt < nk; ++kt) {
    __syncthreads();
    half8v av[4], bv[4];
#pragma unroll
    for (int mf = 0; mf < 4; ++mf)
      av[mf] = *(const half8v*)((const _Float16*)Abuf + abase + mf * 512);
#pragma unroll
    for (int nf = 0; nf < 4; ++nf)
      bv[nf] = *(const half8v*)((const _Float16*)Bbuf + bbase + nf * 512);
#pragma unroll
    for (int mf = 0; mf < 4; ++mf)
#pragma unroll
      for (int nf = 0; nf < 4; ++nf)
        acc[mf][nf] = __builtin_amdgcn_mfma_f32_16x16x32_f16(av[mf], bv[nf], acc[mf][nf], 0, 0, 0);
    __syncthreads();
    if (kt + 1 < nk) STAGE1(kt + 1);
  }
#undef STAGE1
  const int crow0 = tileM + wm * 64 + (l >> 4) * 4;
  const int ccol0 = tileN + wn * 64 + (l & 15);
#pragma unroll
  for (int nf = 0; nf < 4; ++nf) {
    const int col = ccol0 + nf * 16;
    const float bvv = bias[col];
#pragma unroll
    for (int mf = 0; mf < 4; ++mf) {
#pragma unroll
      for (int j = 0; j < 4; ++j) {
        const int row = crow0 + mf * 16 + j;
        float v = fmaxf(acc[mf][nf][j] + bvv, 0.f);
        C[(size_t)row * N + col] = (_Float16)v;
      }
    }
  }
}

// ---------------- GEMM2: 256^2 8-phase, M-quadrant phases (B held in regs) ---
// A: [M][2048] f16, Bt: [6272+pad][2048] f16, C: [M][6400] f16 = A*Bt^T + bias
// Per K-tile (BK=64): 4 phases over M-quadrants; B-frags (8) loaded once at q0.
// ds_read_b128 per K-tile per wave = 8(B) + 16(A) = 24 (vs 48 in r4 — was LDS-bound).
__global__ __launch_bounds__(512, 2) void k_gemm2(
    const _Float16* __restrict__ A, const _Float16* __restrict__ Bt,
    const float* __restrict__ bias, _Float16* __restrict__ C, int M) {
  constexpr int K = HDIM;       // 2048
  constexpr int K2 = K * 2;     // row bytes
  constexpr int NT = K / 64;    // 32 K-tiles
  constexpr int ITERS = NT / 2; // 16

  __shared__ char smem[131072];  // A: [2 dbuf][2 half][16KB] @0; B same @65536

  const int t = threadIdx.x;
  const int l = t & 63;
  const int w = t >> 6;    // 0..7
  const int wm = w >> 2;   // 0..1
  const int wn = w & 3;    // 0..3
  const int rlo = l & 15;
  const int khi = l >> 4;
  const int wOff = w * 1024;

  int bx = blockIdx.x, by = blockIdx.y;
  {
    const int nx = gridDim.x;
    const int nwg = nx * gridDim.y;
    const int lin = by * nx + bx;
    const int cpx = nwg >> 3;
    const int sw = (lin & 7) * cpx + (lin >> 3);
    bx = sw % nx;
    by = sw / nx;
  }
  const int tileM = by * 256;
  const int tileN = bx * 256;

  // staging source decode: LDS phys -> logical (involution: bit9 -> bit5)
  // logical layout per 16KB half-region: [frag(8)][kstep(2)][row16][64B]
  int rowj[2], kbj[2];
#pragma unroll
  for (int j = 0; j < 2; ++j) {
    const int phys = j * 8192 + t * 16;
    const int b = phys ^ (((phys >> 9) & 1) << 5);
    rowj[j] = ((b >> 11) << 4) + ((b >> 6) & 15);
    kbj[j] = (((b >> 10) & 1) << 6) + (b & 63);
  }
  const char* pA[2][2];
  const char* pB[2][2];
#pragma unroll
  for (int half = 0; half < 2; ++half)
#pragma unroll
    for (int j = 0; j < 2; ++j) {
      pA[half][j] = (const char*)A + (size_t)(tileM + half * 128 + rowj[j]) * K2 + kbj[j];
      pB[half][j] = (const char*)Bt + (size_t)(tileN + half * 128 + rowj[j]) * K2 + kbj[j];
    }

  auto lds3 = (__attribute__((address_space(3))) char*)smem;

#define LDSA(d, half) ((d) * 32768 + (half) * 16384)
#define LDSB(d, half) (65536 + (d) * 32768 + (half) * 16384)
#define GLDS(srcp, ldsoff)                                                                   \
  __builtin_amdgcn_global_load_lds(                                                           \
      (const __attribute__((address_space(1))) uint32_t*)(srcp),                              \
      (__attribute__((address_space(3))) uint32_t*)(lds3 + (ldsoff) + wOff), 16, 0, 0)
#define STG(op, d, half, kt)                                                                  \
  do {                                                                                        \
    GLDS(p##op[half][0] + (size_t)(kt) * 128, LDS##op(d, half));                              \
    GLDS(p##op[half][1] + (size_t)(kt) * 128, LDS##op(d, half) + 8192);                       \
  } while (0)
#define VM(n) asm volatile("s_waitcnt vmcnt(" #n ")" ::: "memory")
#define NOSTG ((void)0)
#define NOW ((void)0)
#define CFENCE asm volatile("" ::: "memory")

  // swizzled per-lane byte offset within a frag/kstep block
  const int swz = (rlo & 8) ? 32 : 0;
  const int lane16 = rlo * 64 + ((khi * 16) ^ swz);
  const int aW = wm * 8192 + lane16;           // + d*32768 + (q>>1)*16384 + (q&1)*4096
  const int bW = 65536 + wn * 4096 + lane16;   // + d*32768 + nq*16384 + bf*2048 + ks*1024

  half8v b000, b001, b010, b011, b100, b101, b110, b111;  // live across a K-tile
  f32x4 acc[8][4];
#pragma unroll
  for (int i = 0; i < 8; ++i)
#pragma unroll
    for (int j = 0; j < 4; ++j) acc[i][j] = (f32x4){0.f, 0.f, 0.f, 0.f};

#define MF(fi, gj, av, bv) \
  acc[fi][gj] = __builtin_amdgcn_mfma_f32_16x16x32_f16(av, bv, acc[fi][gj], 0, 0, 0)

// phase: read A-quadrant q of buffer d (+ all B-frags if LOADB), stage, wait,
// barrier, lgkm, 16 MFMA, barrier.
#define PHX(d, q, LOADB, WAITS, ...)                                                          \
  do {                                                                                        \
    const int aB = (d) * 32768 + ((q) >> 1) * 16384 + ((q) & 1) * 4096 + aW;                  \
    half8v a00 = *(const half8v*)(smem + aB);          /* frag0 ks0 */                        \
    half8v a01 = *(const half8v*)(smem + aB + 1024);   /* frag0 ks1 */                        \
    half8v a10 = *(const half8v*)(smem + aB + 2048);   /* frag1 ks0 */                        \
    half8v a11 = *(const half8v*)(smem + aB + 3072);   /* frag1 ks1 */                        \
    if (LOADB) {                                                                              \
      const int bB = (d) * 32768 + bW;                                                        \
      b000 = *(const half8v*)(smem + bB);                                                     \
      b001 = *(const half8v*)(smem + bB + 1024);                                              \
      b010 = *(const half8v*)(smem + bB + 2048);                                              \
      b011 = *(const half8v*)(smem + bB + 3072);                                              \
      b100 = *(const half8v*)(smem + bB + 16384);                                             \
      b101 = *(const half8v*)(smem + bB + 17408);                                             \
      b110 = *(const half8v*)(smem + bB + 18432);                                             \
      b111 = *(const half8v*)(smem + bB + 19456);                                             \
    }                                                                                         \
    __VA_ARGS__;                                                                              \
    WAITS;                                                                                    \
    CFENCE;                                                                                   \
    __builtin_amdgcn_s_barrier();                                                             \
    asm volatile("s_waitcnt lgkmcnt(0)" ::: "memory");                                        \
    __builtin_amdgcn_s_setprio(1);                                                            \
    {                                                                                         \
      constexpr int f0 = ((q) >> 1) * 4 + ((q) & 1) * 2;                                      \
      MF(f0 + 0, 0, a00, b000); MF(f0 + 0, 0, a01, b001);                                     \
      MF(f0 + 0, 1, a00, b010); MF(f0 + 0, 1, a01, b011);                                     \
      MF(f0 + 0, 2, a00, b100); MF(f0 + 0, 2, a01, b101);                                     \
      MF(f0 + 0, 3, a00, b110); MF(f0 + 0, 3, a01, b111);                                     \
      MF(f0 + 1, 0, a10, b000); MF(f0 + 1, 0, a11, b001);                                     \
      MF(f0 + 1, 1, a10, b010); MF(f0 + 1, 1, a11, b011);                                     \
      MF(f0 + 1, 2, a10, b100); MF(f0 + 1, 2, a11, b101);                                     \
      MF(f0 + 1, 3, a10, b110); MF(f0 + 1, 3, a11, b111);                                     \
    }                                                                                         \
    __builtin_amdgcn_s_setprio(0);                                                            \
    CFENCE;                                                                                   \
    __builtin_amdgcn_s_barrier();                                                             \
  } while (0)

  // prologue: tile0 full (8 loads) -> buf0; tile1 B+A-h0 (6 loads) -> buf1
  STG(B, 0, 0, 0);
  STG(B, 0, 1, 0);
  STG(A, 0, 0, 0);
  STG(A, 0, 1, 0);
  STG(B, 1, 0, 1);
  STG(B, 1, 1, 1);
  STG(A, 1, 0, 1);
  VM(6);  // tile0 landed; 6 outstanding (tile1 B,A-h0) = steady-state precondition
  CFENCE;
  __builtin_amdgcn_s_barrier();

  // steady state per iteration (tiles kt->buf0, kt+1->buf1; prefetch kt+2, kt+3):
  //   ph1 stages a=A(b1,h1,kt+1)[2]; ph2 b=B(b0,h0,kt+2)[2]; ph3 c=B(b0,h1)+A(b0,h0)[4];
  //   ph4 VM(8) drains prev e,f (kt+1 B+A-h0, needed ph5/6); ph5 d=A(b0,h1,kt+2)[2];
  //   ph6 e=B(b1,h0,kt+3)[2], VM(10) drains a (kt+1 A-h1, needed ph7/8);
  //   ph7 f=B(b1,h1)+A(b1,h0,kt+3)[4]; ph8 VM(6) drains b,c,d (kt+2, needed next ph1-3).
  for (int it = 0; it < ITERS - 1; ++it) {
    const int kt = 2 * it;
    PHX(0, 0, 1, NOW, STG(A, 1, 1, kt + 1));
    PHX(0, 1, 0, NOW, STG(B, 0, 0, kt + 2));
    PHX(0, 2, 0, NOW, STG(B, 0, 1, kt + 2); STG(A, 0, 0, kt + 2));
    PHX(0, 3, 0, VM(8), NOSTG);
    PHX(1, 0, 1, NOW, STG(A, 0, 1, kt + 2));
    PHX(1, 1, 0, VM(10), STG(B, 1, 0, kt + 3));
    PHX(1, 2, 0, NOW, STG(B, 1, 1, kt + 3); STG(A, 1, 0, kt + 3));
    PHX(1, 3, 0, VM(6), NOSTG);
  }
  // tail: tiles NT-2 (buf0), NT-1 (buf1); only A(b1,h1,NT-1) left to stage
  PHX(0, 0, 1, NOW, STG(A, 1, 1, NT - 1));
  PHX(0, 1, 0, NOW, NOSTG);
  PHX(0, 2, 0, NOW, NOSTG);
  PHX(0, 3, 0, VM(2), NOSTG);
  PHX(1, 0, 1, NOW, NOSTG);
  PHX(1, 1, 0, VM(0), NOSTG);
  PHX(1, 2, 0, NOW, NOSTG);
  PHX(1, 3, 0, NOW, NOSTG);

#undef PHX
#undef MF
#undef STG
#undef GLDS
#undef LDSA
#undef LDSB

  // epilogue: C/D layout col=lane&15, row=(lane>>4)*4+j (m89-verified)
#pragma unroll
  for (int fi = 0; fi < 8; ++fi) {
    const int r0 = tileM + (((fi >> 2) * 2 + wm) << 6) + ((fi & 3) << 4) + khi * 4;
#pragma unroll
    for (int gj = 0; gj < 4; ++gj) {
      const int c = tileN + (((gj >> 1) * 4 + wn) << 5) + ((gj & 1) << 4) + rlo;
      const float bvv = (c < NCOL) ? bias[c] : 0.f;
#pragma unroll
      for (int j = 0; j < 4; ++j)
        C[(size_t)(r0 + j) * NPAD + c] = (_Float16)(acc[fi][gj][j] + bvv);
    }
  }
}

// ---------------- spline epilogue ----------------
__global__ __launch_bounds__(128) void k_spline(
    const _Float16* __restrict__ pdf,  // [rows][NPAD] f16
    const float* __restrict__ y,       // [rows][DYDIM]
    float* __restrict__ out,           // [rows][DYDIM]
    float* __restrict__ dlogp) {       // [rows]
  alignas(16) __shared__ _Float16 row16[NCOL];
  __shared__ float red[128];
  const int b = blockIdx.x;
  const int d = threadIdx.x;
  const _Float16* p = pdf + (size_t)b * NPAD;
  for (int i = d; i < NCOL / 8; i += 128)
    ((half8v*)row16)[i] = ((const half8v*)p)[i];
  __syncthreads();
  const _Float16* q = &row16[d * NPARAM];

  float mw = -1e30f, mh = -1e30f;
#pragma unroll
  for (int j = 0; j < 16; ++j) {
    mw = fmaxf(mw, (float)q[j]);
    mh = fmaxf(mh, (float)q[16 + j]);
  }
  float sw = 0.f, sh = 0.f;
#pragma unroll
  for (int j = 0; j < 16; ++j) {
    sw += __expf((float)q[j] - mw);
    sh += __expf((float)q[16 + j] - mh);
  }
  const float rw = 0.984f / sw, rh = 0.984f / sh;
  const float yv = y[(size_t)b * DYDIM + d];

  float cws = 0.f, chs = 0.f, xk = 0.f, yk = 0.f, wk = 1.f, hk = 1.f;
  int idx = 0;
#pragma unroll
  for (int j = 0; j < 16; ++j) {
    float wj = 0.001f + rw * __expf((float)q[j] - mw);
    float hj = 0.001f + rh * __expf((float)q[16 + j] - mh);
    if (yv >= cws) { idx = j; xk = cws; yk = chs; wk = wj; hk = hj; }
    cws += wj;
    chs += hj;
  }
  const float du0 = (float)q[32 + idx], du1 = (float)q[33 + idx];
  const float dk  = 0.001f + fmaxf(du0, 0.f) + log1pf(__expf(-fabsf(du0)));
  const float dk1 = 0.001f + fmaxf(du1, 0.f) + log1pf(__expf(-fabsf(du1)));

  const float s = hk / wk;
  const float tt = (yv - xk) / wk;
  const float omt = 1.f - tt;
  const float dnm = s + (dk1 + dk - 2.f * s) * tt * omt;
  const float o = yk + hk * (s * tt * tt + dk * tt * omt) / dnm;
  const float dr = s * s * (dk1 * tt * tt + 2.f * s * tt * omt + dk * omt * omt) / (dnm * dnm);

  out[(size_t)b * DYDIM + d] = o;
  red[d] = __logf(dr);
  __syncthreads();
#pragma unroll
  for (int s2 = 64; s2 > 0; s2 >>= 1) {
    if (d < s2) red[d] += red[d + s2];
    __syncthreads();
  }
  if (d == 0) dlogp[b] = red[0];
}

// ---------------- launch ----------------
extern "C" void kernel_launch(void* const* d_in, const int* in_sizes, int n_in,
                              void* d_out, int out_size, void* d_ws, size_t ws_size,
                              hipStream_t stream) {
  const float* x  = (const float*)d_in[0];
  const float* y  = (const float*)d_in[1];
  const float* W1 = (const float*)d_in[2];
  const float* b1 = (const float*)d_in[3];
  const float* W2 = (const float*)d_in[4];
  const float* b2 = (const float*)d_in[5];
  float* out = (float*)d_out;
  float* dlogp = out + (size_t)B_ROWS * DYDIM;

  // choose chunking by available workspace (deterministic: ws_size fixed per run)
  const size_t rest = ((size_t)NCOL * HDIM + (size_t)B_ROWS * HDIM +
                       (size_t)B_ROWS * DX + (size_t)HDIM * DX) * 2;
  const size_t pdf_full = (size_t)B_ROWS * NPAD * 2;
  const int crows = (ws_size >= pdf_full + rest) ? B_ROWS : 8192;
  const int nchunk = B_ROWS / crows;

  char* ws = (char*)d_ws;
  _Float16* pdfc = (_Float16*)ws;                      // [crows][NPAD]
  _Float16* w2t  = pdfc + (size_t)crows * NPAD;        // [NCOL][HDIM]
  _Float16* h    = w2t + (size_t)NCOL * HDIM;          // [B][HDIM]
  _Float16* xb   = h + (size_t)B_ROWS * HDIM;          // [B][DX]
  _Float16* w1t  = xb + (size_t)B_ROWS * DX;           // [HDIM][DX]

  k_f32_to_f16<<<(B_ROWS * DX + 255) / 256, 256, 0, stream>>>(x, xb, B_ROWS * DX);
  k_transpose_f16<<<dim3(HDIM / 32, DX / 32), dim3(32, 8), 0, stream>>>(W1, w1t, DX, HDIM);
  k_transpose_f16<<<dim3(NCOL / 32, HDIM / 32), dim3(32, 8), 0, stream>>>(W2, w2t, HDIM, NCOL);

  // h = relu(x @ W1 + b1), f16.  grid 16*128=2048 blocks
  k_gemm1<<<dim3(HDIM / 128, B_ROWS / 128), 256, 0, stream>>>(
      xb, w1t, b1, h, B_ROWS, HDIM, DX);

  for (int c = 0; c < nchunk; ++c) {
    const _Float16* hA = h + (size_t)c * crows * HDIM;
    k_gemm2<<<dim3(NPAD / 256, crows / 256), 512, 0, stream>>>(hA, w2t, b2, pdfc, crows);
    k_spline<<<crows, 128, 0, stream>>>(pdfc, y + (size_t)c * crows * DYDIM,
                                        out + (size_t)c * crows * DYDIM,
                                        dlogp + (size_t)c * crows);
  }
}

// Round 6
// 545.043 us; speedup vs baseline: 1.9375x; 1.1027x over previous
//
#include <hip/hip_runtime.h>
#include <hip/hip_fp16.h>
#include <cstdint>
#include <cstddef>

#define B_ROWS 16384
#define DX 128
#define DYDIM 128
#define HDIM 2048
#define NPARAM 49              // 3K+1
#define NCOL 6272              // DYDIM*NPARAM; pdf row stride (16B-aligned: 12544B)
#define NPAD 6400              // 25*256 compute width for 256-tile GEMM2

typedef __attribute__((ext_vector_type(8))) _Float16 half8v;
typedef __attribute__((ext_vector_type(4))) float f32x4;

// ---------------- prep kernels ----------------
__global__ void k_f32_to_f16(const float* __restrict__ in, _Float16* __restrict__ out, int n) {
  int i = blockIdx.x * 256 + threadIdx.x;
  if (i < n) out[i] = (_Float16)in[i];
}

__global__ void k_transpose_f16(const float* __restrict__ in, _Float16* __restrict__ out, int R, int C) {
  __shared__ float tile[32][33];
  int c0 = blockIdx.x * 32, r0 = blockIdx.y * 32;
  int tx = threadIdx.x;
  for (int i = threadIdx.y; i < 32; i += 8)
    tile[i][tx] = in[(size_t)(r0 + i) * C + c0 + tx];
  __syncthreads();
  for (int i = threadIdx.y; i < 32; i += 8)
    out[(size_t)(c0 + i) * R + r0 + tx] = (_Float16)tile[tx][i];
}

// ---------------- GEMM1: m97 128^2 structure (relu, f16 out) ----------------
__global__ __launch_bounds__(256) void k_gemm1(
    const _Float16* __restrict__ A, const _Float16* __restrict__ Bt,
    const float* __restrict__ bias, _Float16* __restrict__ C,
    int M, int N, int K) {
  __shared__ _Float16 Abuf[128 * 32];
  __shared__ _Float16 Bbuf[128 * 32];
  const int t = threadIdx.x;
  const int l = t & 63;
  const int w = t >> 6;
  int bx = blockIdx.x, by = blockIdx.y;
  {
    const int nx = gridDim.x;
    const int nwg = nx * gridDim.y;
    const int lin = by * nx + bx;
    const int cpx = nwg >> 3;
    const int sw = (lin & 7) * cpx + (lin >> 3);
    bx = sw % nx;
    by = sw / nx;
  }
  const int tileM = by * 128;
  const int tileN = bx * 128;
  const int wm = w >> 1, wn = w & 1;
  const int srow = w * 16 + (l >> 2);
  const int skel = (l & 3) * 8;
  const char* Ag = (const char*)(A + (size_t)(tileM + srow) * K + skel);
  const char* Bg = (const char*)(Bt + (size_t)(tileN + srow) * K + skel);
  const size_t gRowStep = (size_t)64 * K * 2;
  auto ldsA = (__attribute__((address_space(3))) char*)Abuf;
  auto ldsB = (__attribute__((address_space(3))) char*)Bbuf;
  const int ldsBase = w * 1024;
  f32x4 acc[4][4];
#pragma unroll
  for (int i = 0; i < 4; ++i)
#pragma unroll
    for (int j = 0; j < 4; ++j) acc[i][j] = (f32x4){0.f, 0.f, 0.f, 0.f};
  const int nk = K >> 5;
#define STAGE1(kt)                                                                             \
  do {                                                                                         \
    size_t koff = (size_t)(kt) * 64;                                                           \
    __builtin_amdgcn_global_load_lds(                                                          \
        (const __attribute__((address_space(1))) uint32_t*)(Ag + koff),                        \
        (__attribute__((address_space(3))) uint32_t*)(ldsA + ldsBase), 16, 0, 0);              \
    __builtin_amdgcn_global_load_lds(                                                          \
        (const __attribute__((address_space(1))) uint32_t*)(Ag + koff + gRowStep),             \
        (__attribute__((address_space(3))) uint32_t*)(ldsA + 4096 + ldsBase), 16, 0, 0);       \
    __builtin_amdgcn_global_load_lds(                                                          \
        (const __attribute__((address_space(1))) uint32_t*)(Bg + koff),                        \
        (__attribute__((address_space(3))) uint32_t*)(ldsB + ldsBase), 16, 0, 0);              \
    __builtin_amdgcn_global_load_lds(                                                          \
        (const __attribute__((address_space(1))) uint32_t*)(Bg + koff + gRowStep),             \
        (__attribute__((address_space(3))) uint32_t*)(ldsB + 4096 + ldsBase), 16, 0, 0);       \
  } while (0)
  STAGE1(0);
  const int abase = (wm * 64 + (l & 15)) * 32 + (l >> 4) * 8;
  const int bbase = (wn * 64 + (l & 15)) * 32 + (l >> 4) * 8;
  for (int kt = 0; kt < nk; ++kt) {
    __syncthreads();
    half8v av[4], bv[4];
#pragma unroll
    for (int mf = 0; mf < 4; ++mf)
      av[mf] = *(const half8v*)((const _Float16*)Abuf + abase + mf * 512);
#pragma unroll
    for (int nf = 0; nf < 4; ++nf)
      bv[nf] = *(const half8v*)((const _Float16*)Bbuf + bbase + nf * 512);
#pragma unroll
    for (int mf = 0; mf < 4; ++mf)
#pragma unroll
      for (int nf = 0; nf < 4; ++nf)
        acc[mf][nf] = __builtin_amdgcn_mfma_f32_16x16x32_f16(av[mf], bv[nf], acc[mf][nf], 0, 0, 0);
    __syncthreads();
    if (kt + 1 < nk) STAGE1(kt + 1);
  }
#undef STAGE1
  const int crow0 = tileM + wm * 64 + (l >> 4) * 4;
  const int ccol0 = tileN + wn * 64 + (l & 15);
#pragma unroll
  for (int nf = 0; nf < 4; ++nf) {
    const int col = ccol0 + nf * 16;
    const float bvv = bias[col];
#pragma unroll
    for (int mf = 0; mf < 4; ++mf) {
#pragma unroll
      for (int j = 0; j < 4; ++j) {
        const int row = crow0 + mf * 16 + j;
        float v = fmaxf(acc[mf][nf][j] + bvv, 0.f);
        C[(size_t)row * N + col] = (_Float16)v;
      }
    }
  }
}

// ---------------- GEMM2: 256^2 8-phase, M-quadrant phases (B held in regs) ---
// A: [M][2048] f16, Bt: [NPAD][2048] f16 (rows >= NCOL are garbage pad),
// C: [M][NCOL] f16 = A*Bt^T + bias (cols >= NCOL discarded).
__global__ __launch_bounds__(512, 2) void k_gemm2(
    const _Float16* __restrict__ A, const _Float16* __restrict__ Bt,
    const float* __restrict__ bias, _Float16* __restrict__ C, int M) {
  constexpr int K = HDIM;       // 2048
  constexpr int K2 = K * 2;     // row bytes
  constexpr int NT = K / 64;    // 32 K-tiles
  constexpr int ITERS = NT / 2; // 16

  __shared__ char smem[131072];  // A: [2 dbuf][2 half][16KB] @0; B same @65536

  const int t = threadIdx.x;
  const int l = t & 63;
  const int w = t >> 6;    // 0..7
  const int wm = w >> 2;   // 0..1
  const int wn = w & 3;    // 0..3
  const int rlo = l & 15;
  const int khi = l >> 4;
  const int wOff = w * 1024;

  int bx = blockIdx.x, by = blockIdx.y;
  {
    const int nx = gridDim.x;
    const int nwg = nx * gridDim.y;
    const int lin = by * nx + bx;
    const int cpx = nwg >> 3;
    const int sw = (lin & 7) * cpx + (lin >> 3);
    bx = sw % nx;
    by = sw / nx;
  }
  const int tileM = by * 256;
  const int tileN = bx * 256;

  // staging source decode: LDS phys -> logical (involution: bit9 -> bit5)
  // logical layout per 16KB half-region: [frag(8)][kstep(2)][row16][64B]
  int rowj[2], kbj[2];
#pragma unroll
  for (int j = 0; j < 2; ++j) {
    const int phys = j * 8192 + t * 16;
    const int b = phys ^ (((phys >> 9) & 1) << 5);
    rowj[j] = ((b >> 11) << 4) + ((b >> 6) & 15);
    kbj[j] = (((b >> 10) & 1) << 6) + (b & 63);
  }
  const char* pA[2][2];
  const char* pB[2][2];
#pragma unroll
  for (int half = 0; half < 2; ++half)
#pragma unroll
    for (int j = 0; j < 2; ++j) {
      pA[half][j] = (const char*)A + (size_t)(tileM + half * 128 + rowj[j]) * K2 + kbj[j];
      pB[half][j] = (const char*)Bt + (size_t)(tileN + half * 128 + rowj[j]) * K2 + kbj[j];
    }

  auto lds3 = (__attribute__((address_space(3))) char*)smem;

#define LDSA(d, half) ((d) * 32768 + (half) * 16384)
#define LDSB(d, half) (65536 + (d) * 32768 + (half) * 16384)
#define GLDS(srcp, ldsoff)                                                                   \
  __builtin_amdgcn_global_load_lds(                                                           \
      (const __attribute__((address_space(1))) uint32_t*)(srcp),                              \
      (__attribute__((address_space(3))) uint32_t*)(lds3 + (ldsoff) + wOff), 16, 0, 0)
#define STG(op, d, half, kt)                                                                  \
  do {                                                                                        \
    GLDS(p##op[half][0] + (size_t)(kt) * 128, LDS##op(d, half));                              \
    GLDS(p##op[half][1] + (size_t)(kt) * 128, LDS##op(d, half) + 8192);                       \
  } while (0)
#define VM(n) asm volatile("s_waitcnt vmcnt(" #n ")" ::: "memory")
#define NOSTG ((void)0)
#define NOW ((void)0)
#define CFENCE asm volatile("" ::: "memory")

  // swizzled per-lane byte offset within a frag/kstep block
  const int swz = (rlo & 8) ? 32 : 0;
  const int lane16 = rlo * 64 + ((khi * 16) ^ swz);
  const int aW = wm * 8192 + lane16;           // + d*32768 + (q>>1)*16384 + (q&1)*4096
  const int bW = 65536 + wn * 4096 + lane16;   // + d*32768 + nq*16384 + bf*2048 + ks*1024

  half8v b000, b001, b010, b011, b100, b101, b110, b111;  // live across a K-tile
  f32x4 acc[8][4];
#pragma unroll
  for (int i = 0; i < 8; ++i)
#pragma unroll
    for (int j = 0; j < 4; ++j) acc[i][j] = (f32x4){0.f, 0.f, 0.f, 0.f};

#define MF(fi, gj, av, bv) \
  acc[fi][gj] = __builtin_amdgcn_mfma_f32_16x16x32_f16(av, bv, acc[fi][gj], 0, 0, 0)

// phase: read A-quadrant q of buffer d (+ all B-frags if LOADB), stage, wait,
// barrier, lgkm, 16 MFMA, barrier.
#define PHX(d, q, LOADB, WAITS, ...)                                                          \
  do {                                                                                        \
    const int aB = (d) * 32768 + ((q) >> 1) * 16384 + ((q) & 1) * 4096 + aW;                  \
    half8v a00 = *(const half8v*)(smem + aB);          /* frag0 ks0 */                        \
    half8v a01 = *(const half8v*)(smem + aB + 1024);   /* frag0 ks1 */                        \
    half8v a10 = *(const half8v*)(smem + aB + 2048);   /* frag1 ks0 */                        \
    half8v a11 = *(const half8v*)(smem + aB + 3072);   /* frag1 ks1 */                        \
    if (LOADB) {                                                                              \
      const int bB = (d) * 32768 + bW;                                                        \
      b000 = *(const half8v*)(smem + bB);                                                     \
      b001 = *(const half8v*)(smem + bB + 1024);                                              \
      b010 = *(const half8v*)(smem + bB + 2048);                                              \
      b011 = *(const half8v*)(smem + bB + 3072);                                              \
      b100 = *(const half8v*)(smem + bB + 16384);                                             \
      b101 = *(const half8v*)(smem + bB + 17408);                                             \
      b110 = *(const half8v*)(smem + bB + 18432);                                             \
      b111 = *(const half8v*)(smem + bB + 19456);                                             \
    }                                                                                         \
    __VA_ARGS__;                                                                              \
    WAITS;                                                                                    \
    CFENCE;                                                                                   \
    __builtin_amdgcn_s_barrier();                                                             \
    asm volatile("s_waitcnt lgkmcnt(0)" ::: "memory");                                        \
    __builtin_amdgcn_s_setprio(1);                                                            \
    {                                                                                         \
      constexpr int f0 = ((q) >> 1) * 4 + ((q) & 1) * 2;                                      \
      MF(f0 + 0, 0, a00, b000); MF(f0 + 0, 0, a01, b001);                                     \
      MF(f0 + 0, 1, a00, b010); MF(f0 + 0, 1, a01, b011);                                     \
      MF(f0 + 0, 2, a00, b100); MF(f0 + 0, 2, a01, b101);                                     \
      MF(f0 + 0, 3, a00, b110); MF(f0 + 0, 3, a01, b111);                                     \
      MF(f0 + 1, 0, a10, b000); MF(f0 + 1, 0, a11, b001);                                     \
      MF(f0 + 1, 1, a10, b010); MF(f0 + 1, 1, a11, b011);                                     \
      MF(f0 + 1, 2, a10, b100); MF(f0 + 1, 2, a11, b101);                                     \
      MF(f0 + 1, 3, a10, b110); MF(f0 + 1, 3, a11, b111);                                     \
    }                                                                                         \
    __builtin_amdgcn_s_setprio(0);                                                            \
    CFENCE;                                                                                   \
    __builtin_amdgcn_s_barrier();                                                             \
  } while (0)

  // prologue: tile0 full (8 loads) -> buf0; tile1 B+A-h0 (6 loads) -> buf1
  STG(B, 0, 0, 0);
  STG(B, 0, 1, 0);
  STG(A, 0, 0, 0);
  STG(A, 0, 1, 0);
  STG(B, 1, 0, 1);
  STG(B, 1, 1, 1);
  STG(A, 1, 0, 1);
  VM(6);  // tile0 landed; 6 outstanding (tile1 B,A-h0) = steady-state precondition
  CFENCE;
  __builtin_amdgcn_s_barrier();

  // steady state per iteration (tiles kt->buf0, kt+1->buf1; prefetch kt+2, kt+3):
  //   ph1 stages a=A(b1,h1,kt+1)[2]; ph2 b=B(b0,h0,kt+2)[2]; ph3 c=B(b0,h1)+A(b0,h0)[4];
  //   ph4 VM(8) drains prev e,f (kt+1 B+A-h0, needed ph5/6); ph5 d=A(b0,h1,kt+2)[2];
  //   ph6 e=B(b1,h0,kt+3)[2], VM(10) drains a (kt+1 A-h1, needed ph7/8);
  //   ph7 f=B(b1,h1)+A(b1,h0,kt+3)[4]; ph8 VM(6) drains b,c,d (kt+2, needed next ph1-3).
  for (int it = 0; it < ITERS - 1; ++it) {
    const int kt = 2 * it;
    PHX(0, 0, 1, NOW, STG(A, 1, 1, kt + 1));
    PHX(0, 1, 0, NOW, STG(B, 0, 0, kt + 2));
    PHX(0, 2, 0, NOW, STG(B, 0, 1, kt + 2); STG(A, 0, 0, kt + 2));
    PHX(0, 3, 0, VM(8), NOSTG);
    PHX(1, 0, 1, NOW, STG(A, 0, 1, kt + 2));
    PHX(1, 1, 0, VM(10), STG(B, 1, 0, kt + 3));
    PHX(1, 2, 0, NOW, STG(B, 1, 1, kt + 3); STG(A, 1, 0, kt + 3));
    PHX(1, 3, 0, VM(6), NOSTG);
  }
  // tail: tiles NT-2 (buf0), NT-1 (buf1); only A(b1,h1,NT-1) left to stage
  PHX(0, 0, 1, NOW, STG(A, 1, 1, NT - 1));
  PHX(0, 1, 0, NOW, NOSTG);
  PHX(0, 2, 0, NOW, NOSTG);
  PHX(0, 3, 0, VM(2), NOSTG);
  PHX(1, 0, 1, NOW, NOSTG);
  PHX(1, 1, 0, VM(0), NOSTG);
  PHX(1, 2, 0, NOW, NOSTG);
  PHX(1, 3, 0, NOW, NOSTG);

#undef PHX
#undef MF
#undef STG
#undef GLDS
#undef LDSA
#undef LDSB

  // epilogue: C/D layout col=lane&15, row=(lane>>4)*4+j (m89-verified)
  // store guarded to c < NCOL (pdf row stride = NCOL)
#pragma unroll
  for (int fi = 0; fi < 8; ++fi) {
    const int r0 = tileM + (((fi >> 2) * 2 + wm) << 6) + ((fi & 3) << 4) + khi * 4;
#pragma unroll
    for (int gj = 0; gj < 4; ++gj) {
      const int c = tileN + (((gj >> 1) * 4 + wn) << 5) + ((gj & 1) << 4) + rlo;
      if (c < NCOL) {
        const float bvv = bias[c];
#pragma unroll
        for (int j = 0; j < 4; ++j)
          C[(size_t)(r0 + j) * NCOL + c] = (_Float16)(acc[fi][gj][j] + bvv);
      }
    }
  }
}

// ---------------- spline epilogue ----------------
__global__ __launch_bounds__(128) void k_spline(
    const _Float16* __restrict__ pdf,  // [rows][NCOL] f16
    const float* __restrict__ y,       // [rows][DYDIM]
    float* __restrict__ out,           // [rows][DYDIM]
    float* __restrict__ dlogp) {       // [rows]
  alignas(16) __shared__ _Float16 row16[NCOL];
  __shared__ float red[128];
  const int b = blockIdx.x;
  const int d = threadIdx.x;
  const _Float16* p = pdf + (size_t)b * NCOL;
  for (int i = d; i < NCOL / 8; i += 128)
    ((half8v*)row16)[i] = ((const half8v*)p)[i];
  __syncthreads();
  const _Float16* q = &row16[d * NPARAM];

  float mw = -1e30f, mh = -1e30f;
#pragma unroll
  for (int j = 0; j < 16; ++j) {
    mw = fmaxf(mw, (float)q[j]);
    mh = fmaxf(mh, (float)q[16 + j]);
  }
  float sw = 0.f, sh = 0.f;
#pragma unroll
  for (int j = 0; j < 16; ++j) {
    sw += __expf((float)q[j] - mw);
    sh += __expf((float)q[16 + j] - mh);
  }
  const float rw = 0.984f / sw, rh = 0.984f / sh;
  const float yv = y[(size_t)b * DYDIM + d];

  float cws = 0.f, chs = 0.f, xk = 0.f, yk = 0.f, wk = 1.f, hk = 1.f;
  int idx = 0;
#pragma unroll
  for (int j = 0; j < 16; ++j) {
    float wj = 0.001f + rw * __expf((float)q[j] - mw);
    float hj = 0.001f + rh * __expf((float)q[16 + j] - mh);
    if (yv >= cws) { idx = j; xk = cws; yk = chs; wk = wj; hk = hj; }
    cws += wj;
    chs += hj;
  }
  const float du0 = (float)q[32 + idx], du1 = (float)q[33 + idx];
  const float dk  = 0.001f + fmaxf(du0, 0.f) + log1pf(__expf(-fabsf(du0)));
  const float dk1 = 0.001f + fmaxf(du1, 0.f) + log1pf(__expf(-fabsf(du1)));

  const float s = hk / wk;
  const float tt = (yv - xk) / wk;
  const float omt = 1.f - tt;
  const float dnm = s + (dk1 + dk - 2.f * s) * tt * omt;
  const float o = yk + hk * (s * tt * tt + dk * tt * omt) / dnm;
  const float dr = s * s * (dk1 * tt * tt + 2.f * s * tt * omt + dk * omt * omt) / (dnm * dnm);

  out[(size_t)b * DYDIM + d] = o;
  red[d] = __logf(dr);
  __syncthreads();
#pragma unroll
  for (int s2 = 64; s2 > 0; s2 >>= 1) {
    if (d < s2) red[d] += red[d + s2];
    __syncthreads();
  }
  if (d == 0) dlogp[b] = red[0];
}

// ---------------- launch ----------------
extern "C" void kernel_launch(void* const* d_in, const int* in_sizes, int n_in,
                              void* d_out, int out_size, void* d_ws, size_t ws_size,
                              hipStream_t stream) {
  const float* x  = (const float*)d_in[0];
  const float* y  = (const float*)d_in[1];
  const float* W1 = (const float*)d_in[2];
  const float* b1 = (const float*)d_in[3];
  const float* W2 = (const float*)d_in[4];
  const float* b2 = (const float*)d_in[5];
  float* out = (float*)d_out;
  float* dlogp = out + (size_t)B_ROWS * DYDIM;

  // ws layout: [w2t: NPAD x HDIM][h: B x HDIM][pdf: crows x NCOL]
  // xb/w1t alias the pdf region (dead before gemm2 writes pdf).
  char* ws = (char*)d_ws;
  _Float16* w2t = (_Float16*)ws;                       // [NPAD][HDIM] (pad rows garbage)
  _Float16* h   = w2t + (size_t)NPAD * HDIM;           // [B][HDIM]
  _Float16* pdf = h + (size_t)B_ROWS * HDIM;           // [crows][NCOL]
  _Float16* xb  = pdf;                                 // [B][DX]   (aliased)
  _Float16* w1t = xb + (size_t)B_ROWS * DX;            // [HDIM][DX] (aliased)

  // pick the largest M-chunk that fits ws (all multiples of 256; grids %8==0)
  const size_t fixed = ((size_t)NPAD * HDIM + (size_t)B_ROWS * HDIM) * 2;
  int crows = 8192;
  if (ws_size >= fixed + (size_t)16384 * NCOL * 2)       crows = 16384;
  else if (ws_size >= fixed + (size_t)14336 * NCOL * 2)  crows = 14336;
  else if (ws_size >= fixed + (size_t)12288 * NCOL * 2)  crows = 12288;

  k_f32_to_f16<<<(B_ROWS * DX + 255) / 256, 256, 0, stream>>>(x, xb, B_ROWS * DX);
  k_transpose_f16<<<dim3(HDIM / 32, DX / 32), dim3(32, 8), 0, stream>>>(W1, w1t, DX, HDIM);
  k_transpose_f16<<<dim3(NCOL / 32, HDIM / 32), dim3(32, 8), 0, stream>>>(W2, w2t, HDIM, NCOL);

  // h = relu(x @ W1 + b1), f16.  grid 16*128=2048 blocks
  k_gemm1<<<dim3(HDIM / 128, B_ROWS / 128), 256, 0, stream>>>(
      xb, w1t, b1, h, B_ROWS, HDIM, DX);

  int done = 0;
  while (done < B_ROWS) {
    const int cr = (B_ROWS - done < crows) ? (B_ROWS - done) : crows;
    k_gemm2<<<dim3(NPAD / 256, cr / 256), 512, 0, stream>>>(
        h + (size_t)done * HDIM, w2t, b2, pdf, cr);
    k_spline<<<cr, 128, 0, stream>>>(pdf, y + (size_t)done * DYDIM,
                                     out + (size_t)done * DYDIM, dlogp + done);
    done += cr;
  }
}

// Round 7
// 502.674 us; speedup vs baseline: 2.1008x; 1.0843x over previous
//
#include <hip/hip_runtime.h>
#include <hip/hip_fp16.h>
#include <cstdint>
#include <cstddef>

#define B_ROWS 16384
#define DX 128
#define DYDIM 128
#define HDIM 2048
#define NPARAM 49              // 3K+1
#define NCOL 6272              // DYDIM*NPARAM
#define NTILES 26              // ceil(128 dims / 5 dims-per-tile)
#define W2PROWS (NTILES * 256) // 6656 permuted W2 rows

typedef __attribute__((ext_vector_type(8))) _Float16 half8v;
typedef __attribute__((ext_vector_type(4))) float f32x4;

// ---------------- prep kernels ----------------
__global__ void k_f32_to_f16(const float* __restrict__ in, _Float16* __restrict__ out, int n) {
  int i = blockIdx.x * 256 + threadIdx.x;
  if (i < n) out[i] = (_Float16)in[i];
}

__global__ void k_transpose_f16(const float* __restrict__ in, _Float16* __restrict__ out, int R, int C) {
  __shared__ float tile[32][33];
  int c0 = blockIdx.x * 32, r0 = blockIdx.y * 32;
  int tx = threadIdx.x;
  for (int i = threadIdx.y; i < 32; i += 8)
    tile[i][tx] = in[(size_t)(r0 + i) * C + c0 + tx];
  __syncthreads();
  for (int i = threadIdx.y; i < 32; i += 8)
    out[(size_t)(c0 + i) * R + r0 + tx] = (_Float16)tile[tx][i];
}

// W2 [2048][6272] f32 -> w2t_perm [6656][2048] f16:
// global col g -> tile t=g/245, within-tile col cc=g%245 -> perm row t*256+cc.
// Pad rows (cc in [245,256)) are never written; their MFMA results are discarded.
__global__ void k_transpose_perm(const float* __restrict__ in, _Float16* __restrict__ out) {
  __shared__ float tile[32][33];
  int c0 = blockIdx.x * 32, r0 = blockIdx.y * 32;
  int tx = threadIdx.x;
  for (int i = threadIdx.y; i < 32; i += 8)
    tile[i][tx] = in[(size_t)(r0 + i) * NCOL + c0 + tx];
  __syncthreads();
  for (int i = threadIdx.y; i < 32; i += 8) {
    int g = c0 + i;
    int t = g / 245;
    int cc = g - t * 245;
    out[(size_t)(t * 256 + cc) * HDIM + r0 + tx] = (_Float16)tile[tx][i];
  }
}

// ---------------- GEMM1: m97 128^2 structure (relu, f16 out) ----------------
__global__ __launch_bounds__(256) void k_gemm1(
    const _Float16* __restrict__ A, const _Float16* __restrict__ Bt,
    const float* __restrict__ bias, _Float16* __restrict__ C,
    int M, int N, int K) {
  __shared__ _Float16 Abuf[128 * 32];
  __shared__ _Float16 Bbuf[128 * 32];
  const int t = threadIdx.x;
  const int l = t & 63;
  const int w = t >> 6;
  int bx = blockIdx.x, by = blockIdx.y;
  {
    const int nx = gridDim.x;
    const int nwg = nx * gridDim.y;
    const int lin = by * nx + bx;
    const int cpx = nwg >> 3;
    const int sw = (lin & 7) * cpx + (lin >> 3);
    bx = sw % nx;
    by = sw / nx;
  }
  const int tileM = by * 128;
  const int tileN = bx * 128;
  const int wm = w >> 1, wn = w & 1;
  const int srow = w * 16 + (l >> 2);
  const int skel = (l & 3) * 8;
  const char* Ag = (const char*)(A + (size_t)(tileM + srow) * K + skel);
  const char* Bg = (const char*)(Bt + (size_t)(tileN + srow) * K + skel);
  const size_t gRowStep = (size_t)64 * K * 2;
  auto ldsA = (__attribute__((address_space(3))) char*)Abuf;
  auto ldsB = (__attribute__((address_space(3))) char*)Bbuf;
  const int ldsBase = w * 1024;
  f32x4 acc[4][4];
#pragma unroll
  for (int i = 0; i < 4; ++i)
#pragma unroll
    for (int j = 0; j < 4; ++j) acc[i][j] = (f32x4){0.f, 0.f, 0.f, 0.f};
  const int nk = K >> 5;
#define STAGE1(kt)                                                                             \
  do {                                                                                         \
    size_t koff = (size_t)(kt) * 64;                                                           \
    __builtin_amdgcn_global_load_lds(                                                          \
        (const __attribute__((address_space(1))) uint32_t*)(Ag + koff),                        \
        (__attribute__((address_space(3))) uint32_t*)(ldsA + ldsBase), 16, 0, 0);              \
    __builtin_amdgcn_global_load_lds(                                                          \
        (const __attribute__((address_space(1))) uint32_t*)(Ag + koff + gRowStep),             \
        (__attribute__((address_space(3))) uint32_t*)(ldsA + 4096 + ldsBase), 16, 0, 0);       \
    __builtin_amdgcn_global_load_lds(                                                          \
        (const __attribute__((address_space(1))) uint32_t*)(Bg + koff),                        \
        (__attribute__((address_space(3))) uint32_t*)(ldsB + ldsBase), 16, 0, 0);              \
    __builtin_amdgcn_global_load_lds(                                                          \
        (const __attribute__((address_space(1))) uint32_t*)(Bg + koff + gRowStep),             \
        (__attribute__((address_space(3))) uint32_t*)(ldsB + 4096 + ldsBase), 16, 0, 0);       \
  } while (0)
  STAGE1(0);
  const int abase = (wm * 64 + (l & 15)) * 32 + (l >> 4) * 8;
  const int bbase = (wn * 64 + (l & 15)) * 32 + (l >> 4) * 8;
  for (int kt = 0; kt < nk; ++kt) {
    __syncthreads();
    half8v av[4], bv[4];
#pragma unroll
    for (int mf = 0; mf < 4; ++mf)
      av[mf] = *(const half8v*)((const _Float16*)Abuf + abase + mf * 512);
#pragma unroll
    for (int nf = 0; nf < 4; ++nf)
      bv[nf] = *(const half8v*)((const _Float16*)Bbuf + bbase + nf * 512);
#pragma unroll
    for (int mf = 0; mf < 4; ++mf)
#pragma unroll
      for (int nf = 0; nf < 4; ++nf)
        acc[mf][nf] = __builtin_amdgcn_mfma_f32_16x16x32_f16(av[mf], bv[nf], acc[mf][nf], 0, 0, 0);
    __syncthreads();
    if (kt + 1 < nk) STAGE1(kt + 1);
  }
#undef STAGE1
  const int crow0 = tileM + wm * 64 + (l >> 4) * 4;
  const int ccol0 = tileN + wn * 64 + (l & 15);
#pragma unroll
  for (int nf = 0; nf < 4; ++nf) {
    const int col = ccol0 + nf * 16;
    const float bvv = bias[col];
#pragma unroll
    for (int mf = 0; mf < 4; ++mf) {
#pragma unroll
      for (int j = 0; j < 4; ++j) {
        const int row = crow0 + mf * 16 + j;
        float v = fmaxf(acc[mf][nf][j] + bvv, 0.f);
        C[(size_t)row * N + col] = (_Float16)v;
      }
    }
  }
}

// ---------------- GEMM2 + fused spline epilogue -----------------------------
// A: [M][2048] f16 (h), Bt: w2t_perm [6656][2048] f16.
// Each block: 256 rows x 256 cols (= 5 output dims x 49 params + 11 pad).
// K-loop: verified 8-phase schedule (T2 swz + T3/T4 counted vmcnt + T5 setprio).
// Epilogue: acc+bias -> f16 LDS tile (XOR-swizzled) -> in-block rq-spline ->
// out + per-row dlogp partial (deterministic, no atomics).
__global__ __launch_bounds__(512, 2) void k_gemm2s(
    const _Float16* __restrict__ A, const _Float16* __restrict__ Bt,
    const float* __restrict__ bias, const float* __restrict__ y,
    float* __restrict__ outp, float* __restrict__ gpart, int M) {
  constexpr int K = HDIM;       // 2048
  constexpr int K2 = K * 2;     // row bytes
  constexpr int NT = K / 64;    // 32 K-tiles
  constexpr int ITERS = NT / 2; // 16

  __shared__ char smem[131072];  // A: [2 dbuf][2 half][16KB] @0; B same @65536
  __shared__ float red[512];

  const int t = threadIdx.x;
  const int l = t & 63;
  const int w = t >> 6;    // 0..7
  const int wm = w >> 2;   // 0..1
  const int wn = w & 3;    // 0..3
  const int rlo = l & 15;
  const int khi = l >> 4;
  const int wOff = w * 1024;

  int bx = blockIdx.x, by = blockIdx.y;
  {
    const int nx = gridDim.x;
    const int nwg = nx * gridDim.y;
    const int lin = by * nx + bx;
    const int cpx = nwg >> 3;
    const int sw = (lin & 7) * cpx + (lin >> 3);
    bx = sw % nx;
    by = sw / nx;
  }
  const int tileM = by * 256;
  const int tileN = bx * 256;   // row offset into w2t_perm

  // staging source decode: LDS phys -> logical (involution: bit9 -> bit5)
  int rowj[2], kbj[2];
#pragma unroll
  for (int j = 0; j < 2; ++j) {
    const int phys = j * 8192 + t * 16;
    const int b = phys ^ (((phys >> 9) & 1) << 5);
    rowj[j] = ((b >> 11) << 4) + ((b >> 6) & 15);
    kbj[j] = (((b >> 10) & 1) << 6) + (b & 63);
  }
  const char* pA[2][2];
  const char* pB[2][2];
#pragma unroll
  for (int half = 0; half < 2; ++half)
#pragma unroll
    for (int j = 0; j < 2; ++j) {
      pA[half][j] = (const char*)A + (size_t)(tileM + half * 128 + rowj[j]) * K2 + kbj[j];
      pB[half][j] = (const char*)Bt + (size_t)(tileN + half * 128 + rowj[j]) * K2 + kbj[j];
    }

  auto lds3 = (__attribute__((address_space(3))) char*)smem;

#define LDSA(d, half) ((d) * 32768 + (half) * 16384)
#define LDSB(d, half) (65536 + (d) * 32768 + (half) * 16384)
#define GLDS(srcp, ldsoff)                                                                   \
  __builtin_amdgcn_global_load_lds(                                                           \
      (const __attribute__((address_space(1))) uint32_t*)(srcp),                              \
      (__attribute__((address_space(3))) uint32_t*)(lds3 + (ldsoff) + wOff), 16, 0, 0)
#define STG(op, d, half, kt)                                                                  \
  do {                                                                                        \
    GLDS(p##op[half][0] + (size_t)(kt) * 128, LDS##op(d, half));                              \
    GLDS(p##op[half][1] + (size_t)(kt) * 128, LDS##op(d, half) + 8192);                       \
  } while (0)
#define VM(n) asm volatile("s_waitcnt vmcnt(" #n ")" ::: "memory")
#define NOSTG ((void)0)
#define NOW ((void)0)
#define CFENCE asm volatile("" ::: "memory")

  // swizzled per-lane byte offset within a frag/kstep block
  const int swz = (rlo & 8) ? 32 : 0;
  const int lane16 = rlo * 64 + ((khi * 16) ^ swz);
  const int aW = wm * 8192 + lane16;
  const int bW = 65536 + wn * 4096 + lane16;

  half8v b000, b001, b010, b011, b100, b101, b110, b111;  // live across a K-tile
  f32x4 acc[8][4];
#pragma unroll
  for (int i = 0; i < 8; ++i)
#pragma unroll
    for (int j = 0; j < 4; ++j) acc[i][j] = (f32x4){0.f, 0.f, 0.f, 0.f};

#define MF(fi, gj, av, bv) \
  acc[fi][gj] = __builtin_amdgcn_mfma_f32_16x16x32_f16(av, bv, acc[fi][gj], 0, 0, 0)

// phase: read A-quadrant q of buffer d (+ all B-frags if LOADB), stage, wait,
// barrier, (compiler-staggered lgkm waits), 16 MFMA, barrier.
#define PHX(d, q, LOADB, WAITS, ...)                                                          \
  do {                                                                                        \
    const int aB = (d) * 32768 + ((q) >> 1) * 16384 + ((q) & 1) * 4096 + aW;                  \
    half8v a00 = *(const half8v*)(smem + aB);                                                 \
    half8v a01 = *(const half8v*)(smem + aB + 1024);                                          \
    half8v a10 = *(const half8v*)(smem + aB + 2048);                                          \
    half8v a11 = *(const half8v*)(smem + aB + 3072);                                          \
    if (LOADB) {                                                                              \
      const int bB = (d) * 32768 + bW;                                                        \
      b000 = *(const half8v*)(smem + bB);                                                     \
      b001 = *(const half8v*)(smem + bB + 1024);                                              \
      b010 = *(const half8v*)(smem + bB + 2048);                                              \
      b011 = *(const half8v*)(smem + bB + 3072);                                              \
      b100 = *(const half8v*)(smem + bB + 16384);                                             \
      b101 = *(const half8v*)(smem + bB + 17408);                                             \
      b110 = *(const half8v*)(smem + bB + 18432);                                             \
      b111 = *(const half8v*)(smem + bB + 19456);                                             \
    }                                                                                         \
    __VA_ARGS__;                                                                              \
    WAITS;                                                                                    \
    CFENCE;                                                                                   \
    __builtin_amdgcn_s_barrier();                                                             \
    CFENCE;                                                                                   \
    __builtin_amdgcn_s_setprio(1);                                                            \
    {                                                                                         \
      constexpr int f0 = ((q) >> 1) * 4 + ((q) & 1) * 2;                                      \
      MF(f0 + 0, 0, a00, b000); MF(f0 + 0, 0, a01, b001);                                     \
      MF(f0 + 0, 1, a00, b010); MF(f0 + 0, 1, a01, b011);                                     \
      MF(f0 + 0, 2, a00, b100); MF(f0 + 0, 2, a01, b101);                                     \
      MF(f0 + 0, 3, a00, b110); MF(f0 + 0, 3, a01, b111);                                     \
      MF(f0 + 1, 0, a10, b000); MF(f0 + 1, 0, a11, b001);                                     \
      MF(f0 + 1, 1, a10, b010); MF(f0 + 1, 1, a11, b011);                                     \
      MF(f0 + 1, 2, a10, b100); MF(f0 + 1, 2, a11, b101);                                     \
      MF(f0 + 1, 3, a10, b110); MF(f0 + 1, 3, a11, b111);                                     \
    }                                                                                         \
    __builtin_amdgcn_s_setprio(0);                                                            \
    CFENCE;                                                                                   \
    __builtin_amdgcn_s_barrier();                                                             \
  } while (0)

  // prologue: tile0 full (8 loads) -> buf0; tile1 B+A-h0 (6 loads) -> buf1
  STG(B, 0, 0, 0);
  STG(B, 0, 1, 0);
  STG(A, 0, 0, 0);
  STG(A, 0, 1, 0);
  STG(B, 1, 0, 1);
  STG(B, 1, 1, 1);
  STG(A, 1, 0, 1);
  VM(6);
  CFENCE;
  __builtin_amdgcn_s_barrier();

  for (int it = 0; it < ITERS - 1; ++it) {
    const int kt = 2 * it;
    PHX(0, 0, 1, NOW, STG(A, 1, 1, kt + 1));
    PHX(0, 1, 0, NOW, STG(B, 0, 0, kt + 2));
    PHX(0, 2, 0, NOW, STG(B, 0, 1, kt + 2); STG(A, 0, 0, kt + 2));
    PHX(0, 3, 0, VM(8), NOSTG);
    PHX(1, 0, 1, NOW, STG(A, 0, 1, kt + 2));
    PHX(1, 1, 0, VM(10), STG(B, 1, 0, kt + 3));
    PHX(1, 2, 0, NOW, STG(B, 1, 1, kt + 3); STG(A, 1, 0, kt + 3));
    PHX(1, 3, 0, VM(6), NOSTG);
  }
  PHX(0, 0, 1, NOW, STG(A, 1, 1, NT - 1));
  PHX(0, 1, 0, NOW, NOSTG);
  PHX(0, 2, 0, NOW, NOSTG);
  PHX(0, 3, 0, VM(2), NOSTG);
  PHX(1, 0, 1, NOW, NOSTG);
  PHX(1, 1, 0, VM(0), NOSTG);
  PHX(1, 2, 0, NOW, NOSTG);
  PHX(1, 3, 0, NOW, NOSTG);

#undef PHX
#undef MF
#undef STG
#undef GLDS
#undef LDSA
#undef LDSB

  // ---- fused epilogue ------------------------------------------------------
  const int RCt = (bx < 25) ? 245 : 147;  // real cols in this tile
  const int nd  = (bx < 25) ? 5 : 3;      // dims in this tile

  // acc+bias -> f16 LDS tile [256 r][256 c], byte = r*512 + ((2c)^((r&31)<<4))
#pragma unroll
  for (int fi = 0; fi < 8; ++fi) {
    const int r0l = (((fi >> 2) * 2 + wm) << 6) + ((fi & 3) << 4) + khi * 4;
#pragma unroll
    for (int gj = 0; gj < 4; ++gj) {
      const int c = (((gj >> 1) * 4 + wn) << 5) + ((gj & 1) << 4) + rlo;
      if (c < RCt) {
        const float bvv = bias[245 * bx + c];
#pragma unroll
        for (int j = 0; j < 4; ++j) {
          const int r = r0l + j;
          *(_Float16*)(smem + r * 512 + ((2 * c) ^ ((r & 31) << 4))) =
              (_Float16)(acc[fi][gj][j] + bvv);
        }
      }
    }
  }
  __syncthreads();

  // spline: tasks (r,d); pass p: task = p*512+t -> d = task>>8, r = task&255.
  // thread t<256 owns (r=t, d in {0,2,4}); t>=256 owns (r=t-256, d in {1,3}).
  float lsum = 0.f;
#pragma unroll
  for (int pass = 0; pass < 3; ++pass) {
    const int task = pass * 512 + t;
    const int d = task >> 8;
    const int r = task & 255;
    if (d < nd) {
      const int rbase = r * 512;
      const int rswz = (r & 31) << 4;
      const int cb = 2 * (d * 49);
#define LQ(j) ((float)*(const _Float16*)(smem + rbase + ((cb + 2 * (j)) ^ rswz)))
      float mw = -1e30f, mh = -1e30f;
#pragma unroll
      for (int j = 0; j < 16; ++j) {
        mw = fmaxf(mw, LQ(j));
        mh = fmaxf(mh, LQ(16 + j));
      }
      float sw2 = 0.f, sh = 0.f;
#pragma unroll
      for (int j = 0; j < 16; ++j) {
        sw2 += __expf(LQ(j) - mw);
        sh += __expf(LQ(16 + j) - mh);
      }
      const float rw = 0.984f / sw2, rh = 0.984f / sh;
      const int rg = tileM + r;
      const int dg = 5 * bx + d;
      const float yv = y[(size_t)rg * DYDIM + dg];

      float cws = 0.f, chs = 0.f, xk = 0.f, yk = 0.f, wk = 1.f, hk = 1.f;
      int idx = 0;
#pragma unroll
      for (int j = 0; j < 16; ++j) {
        float wj = 0.001f + rw * __expf(LQ(j) - mw);
        float hj = 0.001f + rh * __expf(LQ(16 + j) - mh);
        if (yv >= cws) { idx = j; xk = cws; yk = chs; wk = wj; hk = hj; }
        cws += wj;
        chs += hj;
      }
      const float du0 = LQ(32 + idx), du1 = LQ(33 + idx);
      const float dk  = 0.001f + fmaxf(du0, 0.f) + log1pf(__expf(-fabsf(du0)));
      const float dk1 = 0.001f + fmaxf(du1, 0.f) + log1pf(__expf(-fabsf(du1)));

      const float s = hk / wk;
      const float tt = (yv - xk) / wk;
      const float omt = 1.f - tt;
      const float dnm = s + (dk1 + dk - 2.f * s) * tt * omt;
      const float o = yk + hk * (s * tt * tt + dk * tt * omt) / dnm;
      const float dr = s * s * (dk1 * tt * tt + 2.f * s * tt * omt + dk * omt * omt) / (dnm * dnm);

      outp[(size_t)rg * DYDIM + dg] = o;
      lsum += __logf(dr);
#undef LQ
    }
  }
  red[t] = lsum;
  __syncthreads();
  if (t < 256)
    gpart[(size_t)bx * B_ROWS + (tileM + t)] = red[t] + red[t + 256];
}

// ---------------- dlogp reduce ----------------
__global__ void k_dlogp_reduce(const float* __restrict__ gpart, float* __restrict__ dlogp) {
  int b = blockIdx.x * 256 + threadIdx.x;
  float s = 0.f;
  for (int tt = 0; tt < NTILES; ++tt) s += gpart[(size_t)tt * B_ROWS + b];
  dlogp[b] = s;
}

// ---------------- launch ----------------
extern "C" void kernel_launch(void* const* d_in, const int* in_sizes, int n_in,
                              void* d_out, int out_size, void* d_ws, size_t ws_size,
                              hipStream_t stream) {
  const float* x  = (const float*)d_in[0];
  const float* y  = (const float*)d_in[1];
  const float* W1 = (const float*)d_in[2];
  const float* b1 = (const float*)d_in[3];
  const float* W2 = (const float*)d_in[4];
  const float* b2 = (const float*)d_in[5];
  float* out = (float*)d_out;
  float* dlogp = out + (size_t)B_ROWS * DYDIM;

  // ws: w2p [6656][2048] f16 | h [B][2048] f16 | xb [B][128] f16 | w1t [2048][128] f16
  //     | gpart [26][B] f32   (total ~101 MB)
  char* ws = (char*)d_ws;
  _Float16* w2p = (_Float16*)ws;
  _Float16* h   = w2p + (size_t)W2PROWS * HDIM;
  _Float16* xb  = h + (size_t)B_ROWS * HDIM;
  _Float16* w1t = xb + (size_t)B_ROWS * DX;
  float* gpart  = (float*)(w1t + (size_t)HDIM * DX);

  k_f32_to_f16<<<(B_ROWS * DX + 255) / 256, 256, 0, stream>>>(x, xb, B_ROWS * DX);
  k_transpose_f16<<<dim3(HDIM / 32, DX / 32), dim3(32, 8), 0, stream>>>(W1, w1t, DX, HDIM);
  k_transpose_perm<<<dim3(NCOL / 32, HDIM / 32), dim3(32, 8), 0, stream>>>(W2, w2p);

  // h = relu(x @ W1 + b1), f16.  grid 16*128=2048 blocks
  k_gemm1<<<dim3(HDIM / 128, B_ROWS / 128), 256, 0, stream>>>(
      xb, w1t, b1, h, B_ROWS, HDIM, DX);

  // fused GEMM2+spline: grid 26 x 64 = 1664 blocks (%8==0)
  k_gemm2s<<<dim3(NTILES, B_ROWS / 256), 512, 0, stream>>>(
      h, w2p, b2, y, out, gpart, B_ROWS);

  k_dlogp_reduce<<<B_ROWS / 256, 256, 0, stream>>>(gpart, dlogp);
}

// Round 8
// 489.852 us; speedup vs baseline: 2.1558x; 1.0262x over previous
//
#include <hip/hip_runtime.h>
#include <hip/hip_fp16.h>
#include <cstdint>
#include <cstddef>

#define B_ROWS 16384
#define DX 128
#define DYDIM 128
#define HDIM 2048
#define NPARAM 49              // 3K+1
#define NCOL 6272              // DYDIM*NPARAM
#define NTILES 26              // ceil(128 dims / 5 dims-per-tile)
#define W2PROWS (NTILES * 256) // 6656 permuted W2 rows

typedef __attribute__((ext_vector_type(8))) _Float16 half8v;
typedef __attribute__((ext_vector_type(4))) float f32x4;

// ---------------- prep kernels ----------------
__global__ void k_f32_to_f16(const float* __restrict__ in, _Float16* __restrict__ out, int n) {
  int i = blockIdx.x * 256 + threadIdx.x;
  if (i < n) out[i] = (_Float16)in[i];
}

__global__ void k_transpose_f16(const float* __restrict__ in, _Float16* __restrict__ out, int R, int C) {
  __shared__ float tile[32][33];
  int c0 = blockIdx.x * 32, r0 = blockIdx.y * 32;
  int tx = threadIdx.x;
  for (int i = threadIdx.y; i < 32; i += 8)
    tile[i][tx] = in[(size_t)(r0 + i) * C + c0 + tx];
  __syncthreads();
  for (int i = threadIdx.y; i < 32; i += 8)
    out[(size_t)(c0 + i) * R + r0 + tx] = (_Float16)tile[tx][i];
}

// W2 [2048][6272] f32 -> w2t_perm [6656][2048] f16:
// global col g -> tile t=g/245, cc=g%245 -> perm row t*256+cc.
__global__ void k_transpose_perm(const float* __restrict__ in, _Float16* __restrict__ out) {
  __shared__ float tile[32][33];
  int c0 = blockIdx.x * 32, r0 = blockIdx.y * 32;
  int tx = threadIdx.x;
  for (int i = threadIdx.y; i < 32; i += 8)
    tile[i][tx] = in[(size_t)(r0 + i) * NCOL + c0 + tx];
  __syncthreads();
  for (int i = threadIdx.y; i < 32; i += 8) {
    int g = c0 + i;
    int t = g / 245;
    int cc = g - t * 245;
    out[(size_t)(t * 256 + cc) * HDIM + r0 + tx] = (_Float16)tile[tx][i];
  }
}

// ---------------- GEMM1: m97 128^2 structure (relu, f16 out) ----------------
__global__ __launch_bounds__(256) void k_gemm1(
    const _Float16* __restrict__ A, const _Float16* __restrict__ Bt,
    const float* __restrict__ bias, _Float16* __restrict__ C,
    int M, int N, int K) {
  __shared__ _Float16 Abuf[128 * 32];
  __shared__ _Float16 Bbuf[128 * 32];
  const int t = threadIdx.x;
  const int l = t & 63;
  const int w = t >> 6;
  int bx = blockIdx.x, by = blockIdx.y;
  {
    const int nx = gridDim.x;
    const int nwg = nx * gridDim.y;
    const int lin = by * nx + bx;
    const int cpx = nwg >> 3;
    const int sw = (lin & 7) * cpx + (lin >> 3);
    bx = sw % nx;
    by = sw / nx;
  }
  const int tileM = by * 128;
  const int tileN = bx * 128;
  const int wm = w >> 1, wn = w & 1;
  const int srow = w * 16 + (l >> 2);
  const int skel = (l & 3) * 8;
  const char* Ag = (const char*)(A + (size_t)(tileM + srow) * K + skel);
  const char* Bg = (const char*)(Bt + (size_t)(tileN + srow) * K + skel);
  const size_t gRowStep = (size_t)64 * K * 2;
  auto ldsA = (__attribute__((address_space(3))) char*)Abuf;
  auto ldsB = (__attribute__((address_space(3))) char*)Bbuf;
  const int ldsBase = w * 1024;
  f32x4 acc[4][4];
#pragma unroll
  for (int i = 0; i < 4; ++i)
#pragma unroll
    for (int j = 0; j < 4; ++j) acc[i][j] = (f32x4){0.f, 0.f, 0.f, 0.f};
  const int nk = K >> 5;
#define STAGE1(kt)                                                                             \
  do {                                                                                         \
    size_t koff = (size_t)(kt) * 64;                                                           \
    __builtin_amdgcn_global_load_lds(                                                          \
        (const __attribute__((address_space(1))) uint32_t*)(Ag + koff),                        \
        (__attribute__((address_space(3))) uint32_t*)(ldsA + ldsBase), 16, 0, 0);              \
    __builtin_amdgcn_global_load_lds(                                                          \
        (const __attribute__((address_space(1))) uint32_t*)(Ag + koff + gRowStep),             \
        (__attribute__((address_space(3))) uint32_t*)(ldsA + 4096 + ldsBase), 16, 0, 0);       \
    __builtin_amdgcn_global_load_lds(                                                          \
        (const __attribute__((address_space(1))) uint32_t*)(Bg + koff),                        \
        (__attribute__((address_space(3))) uint32_t*)(ldsB + ldsBase), 16, 0, 0);              \
    __builtin_amdgcn_global_load_lds(                                                          \
        (const __attribute__((address_space(1))) uint32_t*)(Bg + koff + gRowStep),             \
        (__attribute__((address_space(3))) uint32_t*)(ldsB + 4096 + ldsBase), 16, 0, 0);       \
  } while (0)
  STAGE1(0);
  const int abase = (wm * 64 + (l & 15)) * 32 + (l >> 4) * 8;
  const int bbase = (wn * 64 + (l & 15)) * 32 + (l >> 4) * 8;
  for (int kt = 0; kt < nk; ++kt) {
    __syncthreads();
    half8v av[4], bv[4];
#pragma unroll
    for (int mf = 0; mf < 4; ++mf)
      av[mf] = *(const half8v*)((const _Float16*)Abuf + abase + mf * 512);
#pragma unroll
    for (int nf = 0; nf < 4; ++nf)
      bv[nf] = *(const half8v*)((const _Float16*)Bbuf + bbase + nf * 512);
#pragma unroll
    for (int mf = 0; mf < 4; ++mf)
#pragma unroll
      for (int nf = 0; nf < 4; ++nf)
        acc[mf][nf] = __builtin_amdgcn_mfma_f32_16x16x32_f16(av[mf], bv[nf], acc[mf][nf], 0, 0, 0);
    __syncthreads();
    if (kt + 1 < nk) STAGE1(kt + 1);
  }
#undef STAGE1
  const int crow0 = tileM + wm * 64 + (l >> 4) * 4;
  const int ccol0 = tileN + wn * 64 + (l & 15);
#pragma unroll
  for (int nf = 0; nf < 4; ++nf) {
    const int col = ccol0 + nf * 16;
    const float bvv = bias[col];
#pragma unroll
    for (int mf = 0; mf < 4; ++mf) {
#pragma unroll
      for (int j = 0; j < 4; ++j) {
        const int row = crow0 + mf * 16 + j;
        float v = fmaxf(acc[mf][nf][j] + bvv, 0.f);
        C[(size_t)row * N + col] = (_Float16)v;
      }
    }
  }
}

// ---------------- GEMM2 + fused spline epilogue -----------------------------
__global__ __launch_bounds__(512, 2) void k_gemm2s(
    const _Float16* __restrict__ A, const _Float16* __restrict__ Bt,
    const float* __restrict__ bias, const float* __restrict__ y,
    float* __restrict__ outp, float* __restrict__ gpart, int M) {
  constexpr int K = HDIM;       // 2048
  constexpr int K2 = K * 2;     // row bytes
  constexpr int NT = K / 64;    // 32 K-tiles
  constexpr int ITERS = NT / 2; // 16

  __shared__ char smem[131072];  // K-loop staging; reused as col-major C-tile
  __shared__ float red[512];

  const int t = threadIdx.x;
  const int l = t & 63;
  const int w = t >> 6;    // 0..7
  const int wm = w >> 2;   // 0..1
  const int wn = w & 3;    // 0..3
  const int rlo = l & 15;
  const int khi = l >> 4;
  const int wOff = w * 1024;

  // XCD mapping: each XCD owns 8 contiguous by rows, iterates bx-major
  // (concurrent working set ~4 bx-panels + 8 by-panels ~ 12 MB vs 36 MB).
  int bx = blockIdx.x, by = blockIdx.y;   // 26 x 64
  {
    const int lin = by * 26 + bx;
    const int xcd = lin & 7;
    const int slot = lin >> 3;   // 0..207
    bx = slot >> 3;              // 0..25
    by = xcd * 8 + (slot & 7);   // 0..63
  }
  const int tileM = by * 256;
  const int tileN = bx * 256;   // row offset into w2t_perm

  // staging source decode: LDS phys -> logical (involution: bit9 -> bit5)
  int rowj[2], kbj[2];
#pragma unroll
  for (int j = 0; j < 2; ++j) {
    const int phys = j * 8192 + t * 16;
    const int b = phys ^ (((phys >> 9) & 1) << 5);
    rowj[j] = ((b >> 11) << 4) + ((b >> 6) & 15);
    kbj[j] = (((b >> 10) & 1) << 6) + (b & 63);
  }
  const char* pA[2][2];
  const char* pB[2][2];
#pragma unroll
  for (int half = 0; half < 2; ++half)
#pragma unroll
    for (int j = 0; j < 2; ++j) {
      pA[half][j] = (const char*)A + (size_t)(tileM + half * 128 + rowj[j]) * K2 + kbj[j];
      pB[half][j] = (const char*)Bt + (size_t)(tileN + half * 128 + rowj[j]) * K2 + kbj[j];
    }

  auto lds3 = (__attribute__((address_space(3))) char*)smem;

#define LDSA(d, half) ((d) * 32768 + (half) * 16384)
#define LDSB(d, half) (65536 + (d) * 32768 + (half) * 16384)
#define GLDS(srcp, ldsoff)                                                                   \
  __builtin_amdgcn_global_load_lds(                                                           \
      (const __attribute__((address_space(1))) uint32_t*)(srcp),                              \
      (__attribute__((address_space(3))) uint32_t*)(lds3 + (ldsoff) + wOff), 16, 0, 0)
#define STG(op, d, half, kt)                                                                  \
  do {                                                                                        \
    GLDS(p##op[half][0] + (size_t)(kt) * 128, LDS##op(d, half));                              \
    GLDS(p##op[half][1] + (size_t)(kt) * 128, LDS##op(d, half) + 8192);                       \
  } while (0)
#define VM(n) asm volatile("s_waitcnt vmcnt(" #n ")" ::: "memory")
#define NOSTG ((void)0)
#define NOW ((void)0)
#define CFENCE asm volatile("" ::: "memory")

  // swizzled per-lane byte offset within a frag/kstep block
  const int swz = (rlo & 8) ? 32 : 0;
  const int lane16 = rlo * 64 + ((khi * 16) ^ swz);
  const int aW = wm * 8192 + lane16;
  const int bW = 65536 + wn * 4096 + lane16;

  half8v b000, b001, b010, b011, b100, b101, b110, b111;
  f32x4 acc[8][4];
#pragma unroll
  for (int i = 0; i < 8; ++i)
#pragma unroll
    for (int j = 0; j < 4; ++j) acc[i][j] = (f32x4){0.f, 0.f, 0.f, 0.f};

#define MF(fi, gj, av, bv) \
  acc[fi][gj] = __builtin_amdgcn_mfma_f32_16x16x32_f16(av, bv, acc[fi][gj], 0, 0, 0)

// phase: read A-quadrant q of buffer d (+ all B-frags if LOADB), stage, wait,
// barrier, 16 MFMA (8 independent then their 8 dependent partners), barrier.
#define PHX(d, q, LOADB, WAITS, ...)                                                          \
  do {                                                                                        \
    const int aB = (d) * 32768 + ((q) >> 1) * 16384 + ((q) & 1) * 4096 + aW;                  \
    half8v a00 = *(const half8v*)(smem + aB);                                                 \
    half8v a01 = *(const half8v*)(smem + aB + 1024);                                          \
    half8v a10 = *(const half8v*)(smem + aB + 2048);                                          \
    half8v a11 = *(const half8v*)(smem + aB + 3072);                                          \
    if (LOADB) {                                                                              \
      const int bB = (d) * 32768 + bW;                                                        \
      b000 = *(const half8v*)(smem + bB);                                                     \
      b001 = *(const half8v*)(smem + bB + 1024);                                              \
      b010 = *(const half8v*)(smem + bB + 2048);                                              \
      b011 = *(const half8v*)(smem + bB + 3072);                                              \
      b100 = *(const half8v*)(smem + bB + 16384);                                             \
      b101 = *(const half8v*)(smem + bB + 17408);                                             \
      b110 = *(const half8v*)(smem + bB + 18432);                                             \
      b111 = *(const half8v*)(smem + bB + 19456);                                             \
    }                                                                                         \
    __VA_ARGS__;                                                                              \
    WAITS;                                                                                    \
    CFENCE;                                                                                   \
    __builtin_amdgcn_s_barrier();                                                             \
    CFENCE;                                                                                   \
    __builtin_amdgcn_s_setprio(1);                                                            \
    {                                                                                         \
      constexpr int f0 = ((q) >> 1) * 4 + ((q) & 1) * 2;                                      \
      MF(f0 + 0, 0, a00, b000); MF(f0 + 0, 1, a00, b010);                                     \
      MF(f0 + 0, 2, a00, b100); MF(f0 + 0, 3, a00, b110);                                     \
      MF(f0 + 1, 0, a10, b000); MF(f0 + 1, 1, a10, b010);                                     \
      MF(f0 + 1, 2, a10, b100); MF(f0 + 1, 3, a10, b110);                                     \
      MF(f0 + 0, 0, a01, b001); MF(f0 + 0, 1, a01, b011);                                     \
      MF(f0 + 0, 2, a01, b101); MF(f0 + 0, 3, a01, b111);                                     \
      MF(f0 + 1, 0, a11, b001); MF(f0 + 1, 1, a11, b011);                                     \
      MF(f0 + 1, 2, a11, b101); MF(f0 + 1, 3, a11, b111);                                     \
    }                                                                                         \
    __builtin_amdgcn_s_setprio(0);                                                            \
    CFENCE;                                                                                   \
    __builtin_amdgcn_s_barrier();                                                             \
  } while (0)

  // prologue: tile0 full (8 loads) -> buf0; tile1 B+A-h0 (6 loads) -> buf1
  STG(B, 0, 0, 0);
  STG(B, 0, 1, 0);
  STG(A, 0, 0, 0);
  STG(A, 0, 1, 0);
  STG(B, 1, 0, 1);
  STG(B, 1, 1, 1);
  STG(A, 1, 0, 1);
  VM(6);
  CFENCE;
  __builtin_amdgcn_s_barrier();

  for (int it = 0; it < ITERS - 1; ++it) {
    const int kt = 2 * it;
    PHX(0, 0, 1, NOW, STG(A, 1, 1, kt + 1));
    PHX(0, 1, 0, NOW, STG(B, 0, 0, kt + 2));
    PHX(0, 2, 0, NOW, STG(B, 0, 1, kt + 2); STG(A, 0, 0, kt + 2));
    PHX(0, 3, 0, VM(8), NOSTG);
    PHX(1, 0, 1, NOW, STG(A, 0, 1, kt + 2));
    PHX(1, 1, 0, VM(10), STG(B, 1, 0, kt + 3));
    PHX(1, 2, 0, NOW, STG(B, 1, 1, kt + 3); STG(A, 1, 0, kt + 3));
    PHX(1, 3, 0, VM(6), NOSTG);
  }
  PHX(0, 0, 1, NOW, STG(A, 1, 1, NT - 1));
  PHX(0, 1, 0, NOW, NOSTG);
  PHX(0, 2, 0, NOW, NOSTG);
  PHX(0, 3, 0, VM(2), NOSTG);
  PHX(1, 0, 1, NOW, NOSTG);
  PHX(1, 1, 0, VM(0), NOSTG);
  PHX(1, 2, 0, NOW, NOSTG);
  PHX(1, 3, 0, NOW, NOSTG);

#undef PHX
#undef MF
#undef STG
#undef GLDS
#undef LDSA
#undef LDSB

  // ---- fused epilogue ------------------------------------------------------
  const int RCt = (bx < 25) ? 245 : 147;  // real cols in this tile
  const int nd  = (bx < 25) ? 5 : 3;      // dims in this tile

  // C-tile -> LDS col-major: addr(c,r) = c*512 + ((2r) ^ ((c&31)<<4)).
  // Packed u32 (rows r, r+1); alignment/contiguity hold since r0l%4==0 and
  // the XOR operand is a multiple of 16.
#pragma unroll
  for (int fi = 0; fi < 8; ++fi) {
    const int r0l = (((fi >> 2) * 2 + wm) << 6) + ((fi & 3) << 4) + khi * 4;
#pragma unroll
    for (int gj = 0; gj < 4; ++gj) {
      const int c = (((gj >> 1) * 4 + wn) << 5) + ((gj & 1) << 4) + rlo;
      if (c < RCt) {
        const float bvv = bias[245 * bx + c];
        const int cb = c * 512;
        const int cs = (c & 31) << 4;
#pragma unroll
        for (int jp = 0; jp < 2; ++jp) {
          const int r = r0l + jp * 2;
          const unsigned short lo =
              __builtin_bit_cast(unsigned short, (_Float16)(acc[fi][gj][jp * 2] + bvv));
          const unsigned short hi =
              __builtin_bit_cast(unsigned short, (_Float16)(acc[fi][gj][jp * 2 + 1] + bvv));
          *(uint32_t*)(smem + cb + ((2 * r) ^ cs)) = (uint32_t)lo | ((uint32_t)hi << 16);
        }
      }
    }
  }
  __syncthreads();

  // spline: row r = t&255 (constant across passes); dim d = pass*2 + (t>>8).
  const int r = t & 255;
  const int rg = tileM + r;
  float yv_[3];
#pragma unroll
  for (int pass = 0; pass < 3; ++pass) {
    const int d = pass * 2 + (t >> 8);
    yv_[pass] = (d < nd) ? y[(size_t)rg * DYDIM + 5 * bx + d] : 0.f;
  }

#define LDC(p) ((float)*(const _Float16*)(smem + (size_t)(dD * 49 + (p)) * 512 + \
                                          ((2 * r) ^ (((dD * 49 + (p)) & 31) << 4))))
  float lsum = 0.f;
#pragma unroll
  for (int pass = 0; pass < 3; ++pass) {
    const int dD = pass * 2 + (t >> 8);
    if (dD < nd) {
      float qw[16], qh[16], qd[17];
#pragma unroll
      for (int p = 0; p < 16; ++p) { qw[p] = LDC(p); qh[p] = LDC(16 + p); }
#pragma unroll
      for (int p = 0; p < 17; ++p) qd[p] = LDC(32 + p);

      float mw = qw[0], mh = qh[0];
#pragma unroll
      for (int p = 1; p < 16; ++p) { mw = fmaxf(mw, qw[p]); mh = fmaxf(mh, qh[p]); }
      float ew[16], eh[16];
      float sw2 = 0.f, sh = 0.f;
#pragma unroll
      for (int p = 0; p < 16; ++p) {
        ew[p] = __expf(qw[p] - mw);
        eh[p] = __expf(qh[p] - mh);
        sw2 += ew[p];
        sh += eh[p];
      }
      const float rw = 0.984f / sw2, rh = 0.984f / sh;
      const float yv = yv_[pass];

      float cws = 0.f, chs = 0.f, xk = 0.f, yk = 0.f, wk = 1.f, hk = 1.f;
      float du0 = qd[0], du1 = qd[1];
#pragma unroll
      for (int j = 0; j < 16; ++j) {
        float wj = 0.001f + rw * ew[j];
        float hj = 0.001f + rh * eh[j];
        if (yv >= cws) { xk = cws; yk = chs; wk = wj; hk = hj; du0 = qd[j]; du1 = qd[j + 1]; }
        cws += wj;
        chs += hj;
      }
      const float dk  = 0.001f + fmaxf(du0, 0.f) + log1pf(__expf(-fabsf(du0)));
      const float dk1 = 0.001f + fmaxf(du1, 0.f) + log1pf(__expf(-fabsf(du1)));

      const float s = hk / wk;
      const float tt = (yv - xk) / wk;
      const float omt = 1.f - tt;
      const float dnm = s + (dk1 + dk - 2.f * s) * tt * omt;
      const float o = yk + hk * (s * tt * tt + dk * tt * omt) / dnm;
      const float dr = s * s * (dk1 * tt * tt + 2.f * s * tt * omt + dk * omt * omt) / (dnm * dnm);

      outp[(size_t)rg * DYDIM + 5 * bx + dD] = o;
      lsum += __logf(dr);
    }
  }
#undef LDC
  red[t] = lsum;
  __syncthreads();
  if (t < 256)
    gpart[(size_t)bx * B_ROWS + (tileM + t)] = red[t] + red[t + 256];
}

// ---------------- dlogp reduce ----------------
__global__ void k_dlogp_reduce(const float* __restrict__ gpart, float* __restrict__ dlogp) {
  int b = blockIdx.x * 256 + threadIdx.x;
  float s = 0.f;
  for (int tt = 0; tt < NTILES; ++tt) s += gpart[(size_t)tt * B_ROWS + b];
  dlogp[b] = s;
}

// ---------------- launch ----------------
extern "C" void kernel_launch(void* const* d_in, const int* in_sizes, int n_in,
                              void* d_out, int out_size, void* d_ws, size_t ws_size,
                              hipStream_t stream) {
  const float* x  = (const float*)d_in[0];
  const float* y  = (const float*)d_in[1];
  const float* W1 = (const float*)d_in[2];
  const float* b1 = (const float*)d_in[3];
  const float* W2 = (const float*)d_in[4];
  const float* b2 = (const float*)d_in[5];
  float* out = (float*)d_out;
  float* dlogp = out + (size_t)B_ROWS * DYDIM;

  // ws: w2p [6656][2048] f16 | h [B][2048] f16 | xb [B][128] f16 | w1t [2048][128] f16
  //     | gpart [26][B] f32   (total ~101 MB)
  char* ws = (char*)d_ws;
  _Float16* w2p = (_Float16*)ws;
  _Float16* h   = w2p + (size_t)W2PROWS * HDIM;
  _Float16* xb  = h + (size_t)B_ROWS * HDIM;
  _Float16* w1t = xb + (size_t)B_ROWS * DX;
  float* gpart  = (float*)(w1t + (size_t)HDIM * DX);

  k_f32_to_f16<<<(B_ROWS * DX + 255) / 256, 256, 0, stream>>>(x, xb, B_ROWS * DX);
  k_transpose_f16<<<dim3(HDIM / 32, DX / 32), dim3(32, 8), 0, stream>>>(W1, w1t, DX, HDIM);
  k_transpose_perm<<<dim3(NCOL / 32, HDIM / 32), dim3(32, 8), 0, stream>>>(W2, w2p);

  // h = relu(x @ W1 + b1), f16.  grid 16*128=2048 blocks
  k_gemm1<<<dim3(HDIM / 128, B_ROWS / 128), 256, 0, stream>>>(
      xb, w1t, b1, h, B_ROWS, HDIM, DX);

  // fused GEMM2+spline: grid 26 x 64 = 1664 blocks (%8==0)
  k_gemm2s<<<dim3(NTILES, B_ROWS / 256), 512, 0, stream>>>(
      h, w2p, b2, y, out, gpart, B_ROWS);

  k_dlogp_reduce<<<B_ROWS / 256, 256, 0, stream>>>(gpart, dlogp);
}